// Round 3
// baseline (5468.343 us; speedup 1.0000x reference)
//
#include <hip/hip_runtime.h>
#include <math.h>

// Problem constants: B=8, S=224, P=14, D=512, L=6, NPS=16, N=256, G=5, H=2048, iters=12
#define L6 6

typedef __attribute__((ext_vector_type(8))) short bf16x8;   // 8 bf16 in 4 VGPRs
typedef __attribute__((ext_vector_type(4))) float f32x4;    // MFMA accum

#define SH_W_GRP   2097152ull   // 512*2048 hi/lo bf16 (both W1 and W2)
#define SH_A_GRP   2097152ull   // 2048 tok * 512 d hi/lo
#define SH_A_TDOFF 10485760ull  // Atd offset inside Apk (5 groups)

// Exact gelu (erff): r10-proven epilogue.
__device__ __forceinline__ float gelu_exact(float x) {
  return 0.5f * x * (1.0f + erff(x * 0.70710678118654752f));
}

__device__ __forceinline__ unsigned short bf16_rn(float x) {
  unsigned u = __float_as_uint(x);
  unsigned r = u + 0x7FFFu + ((u >> 16) & 1u);
  return (unsigned short)(r >> 16);
}
__device__ __forceinline__ float bf16_f(unsigned short h) {
  return __uint_as_float(((unsigned)h) << 16);
}
__device__ __forceinline__ void split2(float x, unsigned short* h, unsigned short* l) {
  unsigned short hh = bf16_rn(x);
  *h = hh;
  *l = bf16_rn(x - bf16_f(hh));
}
__device__ __forceinline__ int4 pack8(const unsigned short* v) {
  return make_int4((int)((unsigned)v[0] | ((unsigned)v[1] << 16)),
                   (int)((unsigned)v[2] | ((unsigned)v[3] << 16)),
                   (int)((unsigned)v[4] | ((unsigned)v[5] << 16)),
                   (int)((unsigned)v[6] | ((unsigned)v[7] << 16)));
}

__device__ __forceinline__ void gload16(const void* g, void* l) {
  __builtin_amdgcn_global_load_lds(
      (const __attribute__((address_space(1))) void*)g,
      (__attribute__((address_space(3))) void*)l, 16, 0, 0);
}

// ---------------------------------------------------------------------------
// Patch embedding
// ---------------------------------------------------------------------------
__global__ __launch_bounds__(256) void patch_embed(
    const float* __restrict__ img, const float* __restrict__ Wp,
    const float* __restrict__ bp, float* __restrict__ tokens)
{
  __shared__ float xs[588];
  const int bn = blockIdx.x;
  const int b = bn >> 8, n = bn & 255;
  const int i = n >> 4, j = n & 15;
  for (int k = threadIdx.x; k < 588; k += 256) {
    int c = k % 3;
    int t = k / 3;
    int pc = t % 14;
    int pr = t / 14;
    xs[k] = img[(((size_t)(b * 3 + c) * 224) + (i * 14 + pr)) * 224 + (j * 14 + pc)];
  }
  __syncthreads();
  const int d0 = threadIdx.x, d1 = threadIdx.x + 256;
  float a0 = 0.f, a1 = 0.f;
  for (int k = 0; k < 588; ++k) {
    float x = xs[k];
    a0 = fmaf(x, Wp[(size_t)k * 512 + d0], a0);
    a1 = fmaf(x, Wp[(size_t)k * 512 + d1], a1);
  }
  tokens[(size_t)bn * 512 + d0] = a0 + bp[d0];
  tokens[(size_t)bn * 512 + d1] = a1 + bp[d1];
}

// ---------------------------------------------------------------------------
__global__ __launch_bounds__(256) void init_lv_kernel(
    const float* __restrict__ initl, float* __restrict__ lv)
{
  int f = blockIdx.x * 256 + threadIdx.x;
  int d4 = f & 127;
  int l = (f >> 15) % 6;
  float4 v = *(const float4*)(initl + (size_t)l * 512 + d4 * 4);
  *(float4*)(lv + (size_t)f * 4) = v;
}

// ---------------------------------------------------------------------------
// Pack weights fp32 [G][K][N] -> hi/lo bf16 fragment-image.
// ---------------------------------------------------------------------------
__global__ __launch_bounds__(256) void pack_w(
    const float* __restrict__ src, short* __restrict__ dst, int KT, int NT)
{
  int sidx = blockIdx.x * 256 + threadIdx.x;
  int slot = sidx & 511;
  int blk = sidx >> 9;
  int kt = blk % KT;
  int rest = blk / KT;
  int nt = rest % NT;
  int g = rest / NT;
  int f = slot >> 6, lane = slot & 63;
  int N = NT * 128, K = KT * 32;
  int n = nt * 128 + f * 16 + (lane & 15);
  int k0 = kt * 32 + (lane >> 4) * 8;
  const float* s = src + ((size_t)g * K + k0) * N + n;
  unsigned short hi[8], lo[8];
#pragma unroll
  for (int j = 0; j < 8; ++j) split2(s[(size_t)j * N], &hi[j], &lo[j]);
  short* d = dst + (size_t)blk * 8192 + slot * 8;
  *(int4*)d = pack8(hi);
  *(int4*)(d + 4096) = pack8(lo);
}

// ---------------------------------------------------------------------------
// Startup A-pack (steady-state fused into combine3).
// ---------------------------------------------------------------------------
__global__ __launch_bounds__(256) void pack_A(
    const float* __restrict__ lv, const float* __restrict__ pos,
    short* __restrict__ Abu, short* __restrict__ Atd)
{
  const int bx = blockIdx.x;              // 0..1279
  const int lg = bx >> 8, mt = (bx >> 4) & 15, kt = bx & 15;
  const size_t blk = (size_t)bx * 8192;
#pragma unroll
  for (int ss = 0; ss < 2; ++ss) {
    int s = threadIdx.x + ss * 256;
    int f = s >> 6, l = s & 63;
    int m = mt * 128 + (f << 4) + (l & 15);
    int b = m >> 8, n = m & 255;
    int d = kt * 32 + ((l >> 4) << 3);
    const float* pbu = lv + ((size_t)(b * L6 + lg) * 256 + n) * 512 + d;
    const float* ptd = lv + ((size_t)(b * L6 + lg + 1) * 256 + n) * 512 + d;
    const float* pp = pos + (size_t)n * 512 + d;
    float4 u0 = *(const float4*)pbu;
    float4 u1 = *(const float4*)(pbu + 4);
    float xv[8] = {u0.x, u0.y, u0.z, u0.w, u1.x, u1.y, u1.z, u1.w};
    unsigned short hi[8], lo[8];
#pragma unroll
    for (int j = 0; j < 8; ++j) split2(xv[j], &hi[j], &lo[j]);
    *(int4*)(Abu + blk + s * 8) = pack8(hi);
    *(int4*)(Abu + blk + 4096 + s * 8) = pack8(lo);
    float4 v0 = *(const float4*)ptd;
    float4 v1 = *(const float4*)(ptd + 4);
    float4 p0 = *(const float4*)pp;
    float4 p1 = *(const float4*)(pp + 4);
    float yv[8] = {v0.x + p0.x, v0.y + p0.y, v0.z + p0.z, v0.w + p0.w,
                   v1.x + p1.x, v1.y + p1.y, v1.z + p1.z, v1.w + p1.w};
#pragma unroll
    for (int j = 0; j < 8; ++j) split2(yv[j], &hi[j], &lo[j]);
    *(int4*)(Atd + blk + s * 8) = pack8(hi);
    *(int4*)(Atd + blk + 4096 + s * 8) = pack8(lo);
  }
}

// ---------------------------------------------------------------------------
// FF1: h^T = W1^T @ lv^T, bf16x2, 128x128 block, 4 waves.
// r3 (T3/T4/T5): 2-deep LDS dbuf (64KB), RAW s_barrier + COUNTED vmcnt(8)
// (never 0 in loop) so stage(kt+2)'s 8 global_load_lds stay in flight
// across 2 full steps (~600cy window). Step kt:
//   ds_read frags[cur]; lgkmcnt(0)+sched_barrier; s_barrier(A);
//   stage(kt+2 -> buf[cur]); setprio(1); 48 MFMA; setprio(0);
//   vmcnt(8)+sched_barrier; s_barrier(B)   // stage(kt+1) landed
// Wrap-around staging ((kt+2)&15) keeps vmcnt immediate constant; the 2
// wasted tail stages are L2-hits. MFMA order (hh,lh,hl) -> bit-identical.
// ---------------------------------------------------------------------------
__global__ __launch_bounds__(256, 2) void ff1_k(
    const short* __restrict__ Wa, const short* __restrict__ Ap,
    const float* __restrict__ b1, short* __restrict__ hpk)
{
  __shared__ __align__(16) short SA[2][8192];
  __shared__ __align__(16) short SB[2][8192];
  const int per_x = gridDim.x >> 3;
  const int gid = (blockIdx.x & 7) * per_x + (blockIdx.x >> 3);
  const int tt = gid & 15;
  const int tile = gid >> 4;
  const int ht = tile & 15;
  const int z = tile >> 4;
  const int tid = threadIdx.x, lane = tid & 63, w = tid >> 6;
  const int wm = (w >> 1) * 64, wn = (w & 1) * 64;
  const short* ga = Wa + (size_t)(z * 16 + ht) * 16 * 8192;
  const short* gb = Ap + (size_t)(z * 16 + tt) * 16 * 8192;
  const int soff = w * 4096 + lane * 16;

  f32x4 acc[4][4];
#pragma unroll
  for (int i = 0; i < 4; ++i)
#pragma unroll
    for (int j = 0; j < 4; ++j) acc[i][j] = (f32x4)(0.0f);

#define FF1_STG(KT, BUF) do {                                                 \
    const char* pa_ = (const char*)(ga + (size_t)((KT) & 15) * 8192);         \
    const char* pb_ = (const char*)(gb + (size_t)((KT) & 15) * 8192);         \
    _Pragma("unroll")                                                         \
    for (int c = 0; c < 4; ++c) {                                             \
      gload16(pa_ + soff + c * 1024, (char*)SA[BUF] + w * 4096 + c * 1024);   \
      gload16(pb_ + soff + c * 1024, (char*)SB[BUF] + w * 4096 + c * 1024);   \
    }                                                                         \
  } while (0)

  FF1_STG(0, 0);
  FF1_STG(1, 1);
  asm volatile("s_waitcnt vmcnt(8)" ::: "memory");   // stage(0) landed
  __builtin_amdgcn_s_barrier();

  for (int kt = 0; kt < 16; ++kt) {
    const int cur = kt & 1;
    bf16x8 ah[4], al[4], bh[4], bl[4];
#pragma unroll
    for (int i = 0; i < 4; ++i) {
      int f = (wm >> 4) + i;
      ah[i] = *(const bf16x8*)&SA[cur][f * 512 + lane * 8];
      al[i] = *(const bf16x8*)&SA[cur][4096 + f * 512 + lane * 8];
    }
#pragma unroll
    for (int j = 0; j < 4; ++j) {
      int f = (wn >> 4) + j;
      bh[j] = *(const bf16x8*)&SB[cur][f * 512 + lane * 8];
      bl[j] = *(const bf16x8*)&SB[cur][4096 + f * 512 + lane * 8];
    }
    asm volatile("s_waitcnt lgkmcnt(0)" ::: "memory");
    __builtin_amdgcn_sched_barrier(0);
    __builtin_amdgcn_s_barrier();            // (A) all waves done reading cur
    FF1_STG(kt + 2, cur);                    // overwrite cur for step kt+2
    __builtin_amdgcn_s_setprio(1);
    // pass 1: A_hi * B_hi
#pragma unroll
    for (int j = 0; j < 4; ++j)
#pragma unroll
      for (int i = 0; i < 4; ++i)
        acc[i][j] = __builtin_amdgcn_mfma_f32_16x16x32_bf16(
            ah[i], bh[j], acc[i][j], 0, 0, 0);
    // pass 2: A_lo * B_hi
#pragma unroll
    for (int j = 0; j < 4; ++j)
#pragma unroll
      for (int i = 0; i < 4; ++i)
        acc[i][j] = __builtin_amdgcn_mfma_f32_16x16x32_bf16(
            al[i], bh[j], acc[i][j], 0, 0, 0);
    // pass 3: A_hi * B_lo
#pragma unroll
    for (int j = 0; j < 4; ++j)
#pragma unroll
      for (int i = 0; i < 4; ++i)
        acc[i][j] = __builtin_amdgcn_mfma_f32_16x16x32_bf16(
            ah[i], bl[j], acc[i][j], 0, 0, 0);
    __builtin_amdgcn_s_setprio(0);
    asm volatile("s_waitcnt vmcnt(8)" ::: "memory");  // stage(kt+1) landed
    __builtin_amdgcn_sched_barrier(0);
    __builtin_amdgcn_s_barrier();            // (B) buf[kt+1] ready for all
  }
#undef FF1_STG

  const int q = lane >> 4, t = lane & 15;
  const float* b1g = b1 + (size_t)z * 2048;
#pragma unroll
  for (int i = 0; i < 4; ++i) {
    int Hb = ht * 128 + wm + i * 16 + q * 4;
    float4 bv = *(const float4*)(b1g + Hb);
    float bb[4] = {bv.x, bv.y, bv.z, bv.w};
    int kt2 = Hb >> 5;
    int g2 = (Hb >> 3) & 3;
    int jb = Hb & 7;                       // 0 or 4
    size_t blkbase = ((size_t)(z * 16 + tt) * 64 + kt2) * 8192;
#pragma unroll
    for (int j = 0; j < 4; ++j) {
      int f2 = (wn >> 4) + j;
      size_t off = blkbase + (size_t)(f2 * 64 + g2 * 16 + t) * 8 + jb;
      unsigned short hi[4], lo[4];
#pragma unroll
      for (int r = 0; r < 4; ++r) {
        float x = gelu_exact(acc[i][j][r] + bb[r]);
        split2(x, &hi[r], &lo[r]);
      }
      *(uint2*)(hpk + off) =
          make_uint2((unsigned)hi[0] | ((unsigned)hi[1] << 16),
                     (unsigned)hi[2] | ((unsigned)hi[3] << 16));
      *(uint2*)(hpk + off + 4096) =
          make_uint2((unsigned)lo[0] | ((unsigned)lo[1] << 16),
                     (unsigned)lo[2] | ((unsigned)lo[3] << 16));
    }
  }
}

// ---------------------------------------------------------------------------
// Attention + fused norm + softmax -> attnb. Grid 384, XCD-grouped by bl.
// ---------------------------------------------------------------------------
__global__ __launch_bounds__(256) void attn_k(
    const float* __restrict__ lv, float* __restrict__ attnb)
{
  __shared__ __align__(16) char smemraw[38560];
  const int a = blockIdx.x;
  const int s = a >> 3;
  const int bl = (a & 7) * 6 + (s >> 3);
  const int i0 = (s & 7) * 32;
  const float* base = lv + (size_t)bl * 131072;
  float (*Al)[36] = (float(*)[36])smemraw;
  float (*Bst)[257] = (float(*)[257])(smemraw + 4608);
  float* scL = (float*)(smemraw + 4608 + 32896);
  const int tid = threadIdx.x;
  const int ty = tid >> 5, tx = tid & 31;
  float acc[4][8];
#pragma unroll
  for (int i = 0; i < 4; ++i)
#pragma unroll
    for (int j = 0; j < 8; ++j) acc[i][j] = 0.f;
  float ss[8] = {0.f, 0.f, 0.f, 0.f, 0.f, 0.f, 0.f, 0.f};

  for (int k0 = 0; k0 < 512; k0 += 32) {
    {
      int r = tid >> 3, c4 = tid & 7;
      float4 v = *(const float4*)(base + (size_t)(i0 + r) * 512 + k0 + c4 * 4);
      *(float4*)&Al[r][c4 * 4] = v;
    }
#pragma unroll
    for (int it = 0; it < 8; ++it) {
      int f = it * 256 + tid;
      int j = f >> 3, c4 = f & 7;
      float4 v = *(const float4*)(base + (size_t)j * 512 + k0 + c4 * 4);
      Bst[c4 * 4 + 0][j] = v.x;
      Bst[c4 * 4 + 1][j] = v.y;
      Bst[c4 * 4 + 2][j] = v.z;
      Bst[c4 * 4 + 3][j] = v.w;
      ss[it] += v.x * v.x + v.y * v.y + v.z * v.z + v.w * v.w;
    }
    __syncthreads();
#pragma unroll
    for (int kq = 0; kq < 8; ++kq) {
      float4 av4[4];
#pragma unroll
      for (int i = 0; i < 4; ++i) av4[i] = *(const float4*)&Al[ty * 4 + i][kq * 4];
      float av[4][4] = {{av4[0].x, av4[1].x, av4[2].x, av4[3].x},
                        {av4[0].y, av4[1].y, av4[2].y, av4[3].y},
                        {av4[0].z, av4[1].z, av4[2].z, av4[3].z},
                        {av4[0].w, av4[1].w, av4[2].w, av4[3].w}};
#pragma unroll
      for (int c = 0; c < 4; ++c) {
        float bb[8];
#pragma unroll
        for (int j = 0; j < 8; ++j) bb[j] = Bst[kq * 4 + c][tx + j * 32];
#pragma unroll
        for (int i = 0; i < 4; ++i)
#pragma unroll
          for (int j = 0; j < 8; ++j)
            acc[i][j] = fmaf(av[c][i], bb[j], acc[i][j]);
      }
    }
    __syncthreads();
  }

#pragma unroll
  for (int it = 0; it < 8; ++it) {
    float sv = ss[it];
    sv += __shfl_xor(sv, 1);
    sv += __shfl_xor(sv, 2);
    sv += __shfl_xor(sv, 4);
    if ((tid & 7) == 0) scL[(it * 256 + tid) >> 3] = 1.0f / fmaxf(sqrtf(sv), 1e-12f);
  }
  __syncthreads();

  const float rs = 0.04419417382415922f;  // 512^-0.5
#pragma unroll
  for (int ii = 0; ii < 4; ++ii) {
    int i = i0 + ty * 4 + ii;
    float v[8];
    float mx = -1e30f;
#pragma unroll
    for (int jj = 0; jj < 8; ++jj) {
      int j = tx + jj * 32;
      float sv = acc[ii][jj] * scL[j] * rs;
      if (j == i) sv = -0.0005f;
      v[jj] = sv;
      mx = fmaxf(mx, sv);
    }
#pragma unroll
    for (int o = 1; o < 32; o <<= 1) mx = fmaxf(mx, __shfl_xor(mx, o));
    float sum = 0.f;
#pragma unroll
    for (int jj = 0; jj < 8; ++jj) {
      v[jj] = expf(v[jj] - mx);
      sum += v[jj];
    }
#pragma unroll
    for (int o = 1; o < 32; o <<= 1) sum += __shfl_xor(sum, o);
    float inv = 1.0f / sum;
    float* orow = attnb + (size_t)bl * 65536 + (size_t)i * 256;
#pragma unroll
    for (int jj = 0; jj < 8; ++jj) orow[tx + jj * 32] = v[jj] * inv;
  }
}

// ---------------------------------------------------------------------------
// Consensus: accum += attnb @ lv (pure RMW). Grid 768, XCD-grouped by bl.
// ---------------------------------------------------------------------------
__global__ __launch_bounds__(256) void cons_k(
    const float* __restrict__ attnb, const float* __restrict__ lv,
    float* __restrict__ accum)
{
  __shared__ __align__(16) char smemraw[25088];
  const int a = blockIdx.x;
  const int s = a >> 3;
  const int bl = (a & 7) * 6 + (s >> 4);
  const int tile = s & 15;
  int it0 = (tile >> 2) * 64;
  int dt0 = (tile & 3) * 128;
  const float* A = attnb + (size_t)bl * 65536;
  const float* Bm = lv + (size_t)bl * 131072;
  float (*Ast)[68] = (float(*)[68])smemraw;
  float (*Bs)[128] = (float(*)[128])(smemraw + 8704);
  const int tid = threadIdx.x;
  const int ty = tid >> 4, tx = tid & 15;
  float acc[4][8];
#pragma unroll
  for (int i = 0; i < 4; ++i)
#pragma unroll
    for (int j = 0; j < 8; ++j) acc[i][j] = 0.f;

  for (int k0 = 0; k0 < 256; k0 += 32) {
#pragma unroll
    for (int it = 0; it < 2; ++it) {
      int f = it * 256 + tid;
      int r = f >> 3, c4 = f & 7;
      float4 v = *(const float4*)(A + (size_t)(it0 + r) * 256 + k0 + c4 * 4);
      Ast[c4 * 4 + 0][r] = v.x;
      Ast[c4 * 4 + 1][r] = v.y;
      Ast[c4 * 4 + 2][r] = v.z;
      Ast[c4 * 4 + 3][r] = v.w;
    }
#pragma unroll
    for (int it = 0; it < 4; ++it) {
      int kr = (tid >> 5) + it * 8;
      int c4 = tid & 31;
      *(float4*)&Bs[kr][c4 * 4] =
          *(const float4*)(Bm + (size_t)(k0 + kr) * 512 + dt0 + c4 * 4);
    }
    __syncthreads();
#pragma unroll 8
    for (int k = 0; k < 32; ++k) {
      float4 av = *(const float4*)&Ast[k][ty * 4];
      float4 b0 = *(const float4*)&Bs[k][tx * 4];
      float4 b1 = *(const float4*)&Bs[k][64 + tx * 4];
      float avv[4] = {av.x, av.y, av.z, av.w};
      float bv[8] = {b0.x, b0.y, b0.z, b0.w, b1.x, b1.y, b1.z, b1.w};
#pragma unroll
      for (int i = 0; i < 4; ++i)
#pragma unroll
        for (int j = 0; j < 8; ++j)
          acc[i][j] = fmaf(avv[i], bv[j], acc[i][j]);
    }
    __syncthreads();
  }
#pragma unroll
  for (int ii = 0; ii < 4; ++ii) {
    int i = it0 + ty * 4 + ii;
    float* arow = accum + (size_t)bl * 131072 + (size_t)i * 512 + dt0;
#pragma unroll
    for (int j = 0; j < 4; ++j) arow[tx * 4 + j] += acc[ii][j];
#pragma unroll
    for (int j = 0; j < 4; ++j) arow[64 + tx * 4 + j] += acc[ii][4 + j];
  }
}

// ---------------------------------------------------------------------------
// FF2: 64(token) x 128(outd) block, 640 blocks, 4 waves.
// r3: same T4 counted-vmcnt schedule as ff1_k. Stage = 6 gloads/thread ->
// vmcnt(6). Dbuf LDS 48KB -> 3 blocks/CU.
//  emode 0 (bu):      accum = lv + v            (store, levels 1..5)
//  emode 1 (td):      l==0: accum=lv+tokens+v;  else accum += v
// ---------------------------------------------------------------------------
__global__ __launch_bounds__(256, 3) void mfma_ff2(
    const short* __restrict__ hpk, const short* __restrict__ Wb,
    const float* __restrict__ b2, const float* __restrict__ lv,
    const float* __restrict__ tokens, float* __restrict__ accum,
    int olvbase, int emode)
{
  const int per_x = gridDim.x >> 3;
  const int gid = (blockIdx.x & 7) * per_x + (blockIdx.x >> 3);
  const int nt2 = gid & 3;
  const int tile = gid >> 2;
  const int mt2 = tile & 31;          // 64-token tiles
  const int z = tile >> 5;

  __shared__ __align__(16) short SA[2][4096];   // hi 2048 | lo 2048 (per buf)
  __shared__ __align__(16) short SB[2][8192];   // hi 4096 | lo 4096 (per buf)
  const int tid = threadIdx.x, lane = tid & 63, w = tid >> 6;
  const int wm = (w >> 1) * 32, wn = (w & 1) * 64;
  const short* gaBase = hpk + (size_t)(z * 16 + (mt2 >> 1)) * 64 * 8192
                        + (size_t)(mt2 & 1) * 2048;
  const short* gb = Wb + (size_t)(z * 4 + nt2) * 64 * 8192;

  f32x4 acc[2][4];
#pragma unroll
  for (int i = 0; i < 2; ++i)
#pragma unroll
    for (int j = 0; j < 4; ++j) acc[i][j] = (f32x4)(0.0f);

#define FF2_STG(KT, BUF) do {                                                 \
    const char* pa_ = (const char*)(gaBase + (size_t)((KT) & 63) * 8192);     \
    const char* pb_ = (const char*)(gb + (size_t)((KT) & 63) * 8192);         \
    gload16(pa_ + w * 1024 + lane * 16, (char*)SA[BUF] + w * 1024);           \
    gload16(pa_ + 8192 + w * 1024 + lane * 16,                                \
            (char*)SA[BUF] + 4096 + w * 1024);                                \
    _Pragma("unroll")                                                         \
    for (int c = 0; c < 4; ++c)                                               \
      gload16(pb_ + w * 4096 + c * 1024 + lane * 16,                          \
              (char*)SB[BUF] + w * 4096 + c * 1024);                          \
  } while (0)

  FF2_STG(0, 0);
  FF2_STG(1, 1);
  asm volatile("s_waitcnt vmcnt(6)" ::: "memory");   // stage(0) landed
  __builtin_amdgcn_s_barrier();

  for (int kt = 0; kt < 64; ++kt) {
    const int cur = kt & 1;
    bf16x8 ah[2], al[2], bh[4], bl[4];
#pragma unroll
    for (int i = 0; i < 2; ++i) {
      int f = (wm >> 4) + i;
      ah[i] = *(const bf16x8*)&SA[cur][f * 512 + lane * 8];
      al[i] = *(const bf16x8*)&SA[cur][2048 + f * 512 + lane * 8];
    }
#pragma unroll
    for (int j = 0; j < 4; ++j) {
      int f = (wn >> 4) + j;
      bh[j] = *(const bf16x8*)&SB[cur][f * 512 + lane * 8];
      bl[j] = *(const bf16x8*)&SB[cur][4096 + f * 512 + lane * 8];
    }
    asm volatile("s_waitcnt lgkmcnt(0)" ::: "memory");
    __builtin_amdgcn_sched_barrier(0);
    __builtin_amdgcn_s_barrier();            // (A)
    FF2_STG(kt + 2, cur);
    __builtin_amdgcn_s_setprio(1);
#pragma unroll
    for (int j = 0; j < 4; ++j)
#pragma unroll
      for (int i = 0; i < 2; ++i)
        acc[i][j] = __builtin_amdgcn_mfma_f32_16x16x32_bf16(
            ah[i], bh[j], acc[i][j], 0, 0, 0);
#pragma unroll
    for (int j = 0; j < 4; ++j)
#pragma unroll
      for (int i = 0; i < 2; ++i)
        acc[i][j] = __builtin_amdgcn_mfma_f32_16x16x32_bf16(
            al[i], bh[j], acc[i][j], 0, 0, 0);
#pragma unroll
    for (int j = 0; j < 4; ++j)
#pragma unroll
      for (int i = 0; i < 2; ++i)
        acc[i][j] = __builtin_amdgcn_mfma_f32_16x16x32_bf16(
            ah[i], bl[j], acc[i][j], 0, 0, 0);
    __builtin_amdgcn_s_setprio(0);
    asm volatile("s_waitcnt vmcnt(6)" ::: "memory");  // stage(kt+1) landed
    __builtin_amdgcn_sched_barrier(0);
    __builtin_amdgcn_s_barrier();            // (B)
  }
#undef FF2_STG

  const int q = lane >> 4, t = lane & 15;
  const float* b2g = b2 + (size_t)z * 512;
  const int level = olvbase + z;
#pragma unroll
  for (int i = 0; i < 2; ++i) {
#pragma unroll
    for (int r = 0; r < 4; ++r) {
      int m = mt2 * 64 + wm + i * 16 + q * 4 + r;
      int b = m >> 8, n = m & 255;
      size_t rowoff = ((size_t)(b * L6 + level) * 256 + n) * 512;
      float* arow = accum + rowoff;
      const float* lrow = lv + rowoff;
      const float* trow = tokens + (size_t)m * 512;
#pragma unroll
      for (int j = 0; j < 4; ++j) {
        int col = nt2 * 128 + wn + j * 16 + t;
        float v = acc[i][j][r] + b2g[col];
        if (emode == 0)                       arow[col] = lrow[col] + v;
        else if (level == 0)                  arow[col] = lrow[col] + trow[col] + v;
        else                                  arow[col] += v;
      }
    }
  }
}

// ---------------------------------------------------------------------------
// combine3: lv = accum/contrib, write dout on last iter, fused next-iter
// A-packing. Grid 3072.
// ---------------------------------------------------------------------------
__global__ __launch_bounds__(256) void combine3(
    const float* __restrict__ accum, const float* __restrict__ pos,
    float* __restrict__ lv_out, short* __restrict__ Abu,
    short* __restrict__ Atd, float* __restrict__ dout, int last)
{
  int t = blockIdx.x * 256 + threadIdx.x;   // 786,432 total
  int d8 = t & 63;
  int n = (t >> 6) & 255;
  int v = t >> 14;                          // b*6 + l, 0..47
  int l = v % 6, b = v / 6;
  int bn = (b << 8) | n;
  size_t idx = ((size_t)v * 256 + n) * 512 + d8 * 8;
  float4 a0 = *(const float4*)(accum + idx);
  float4 a1 = *(const float4*)(accum + idx + 4);
  float sc = (l == 5) ? (1.0f / 3.0f) : 0.25f;
  float r[8];
  r[0] = a0.x * sc; r[1] = a0.y * sc; r[2] = a0.z * sc; r[3] = a0.w * sc;
  r[4] = a1.x * sc; r[5] = a1.y * sc; r[6] = a1.z * sc; r[7] = a1.w * sc;
  *(float4*)(lv_out + idx) = make_float4(r[0], r[1], r[2], r[3]);
  *(float4*)(lv_out + idx + 4) = make_float4(r[4], r[5], r[6], r[7]);
  if (last) {
    float* dp = dout + ((size_t)bn * 6 + l) * 512 + d8 * 8;
    *(float4*)dp = make_float4(r[0], r[1], r[2], r[3]);
    *(float4*)(dp + 4) = make_float4(r[4], r[5], r[6], r[7]);
  }
  int m = bn;
  int mt = m >> 7;
  int kt = d8 >> 2;
  int s = (((m & 127) >> 4) << 6) | (((d8 & 3) << 4) | (m & 15));
  unsigned short hi[8], lo[8];
  if (l < 5) {
    size_t blk = ((size_t)(l * 16 + mt) * 16 + kt) * 8192;
#pragma unroll
    for (int j = 0; j < 8; ++j) split2(r[j], &hi[j], &lo[j]);
    *(int4*)(Abu + blk + s * 8) = pack8(hi);
    *(int4*)(Abu + blk + 4096 + s * 8) = pack8(lo);
  }
  if (l >= 1) {
    const float* pp = pos + (size_t)n * 512 + d8 * 8;
    float4 p0 = *(const float4*)pp;
    float4 p1 = *(const float4*)(pp + 4);
    float y[8] = {r[0] + p0.x, r[1] + p0.y, r[2] + p0.z, r[3] + p0.w,
                  r[4] + p1.x, r[5] + p1.y, r[6] + p1.z, r[7] + p1.w};
    size_t blk = ((size_t)((l - 1) * 16 + mt) * 16 + kt) * 8192;
#pragma unroll
    for (int j = 0; j < 8; ++j) split2(y[j], &hi[j], &lo[j]);
    *(int4*)(Atd + blk + s * 8) = pack8(hi);
    *(int4*)(Atd + blk + 4096 + s * 8) = pack8(lo);
  }
}

// ---------------------------------------------------------------------------
extern "C" void kernel_launch(void* const* d_in, const int* in_sizes, int n_in,
                              void* d_out, int out_size, void* d_ws, size_t ws_size,
                              hipStream_t stream)
{
  const float* img   = (const float*)d_in[0];
  const float* Wp    = (const float*)d_in[1];
  const float* bp    = (const float*)d_in[2];
  const float* pos   = (const float*)d_in[3];
  const float* initl = (const float*)d_in[4];
  const float* buW1  = (const float*)d_in[5];
  const float* bub1  = (const float*)d_in[6];
  const float* buW2  = (const float*)d_in[7];
  const float* bub2  = (const float*)d_in[8];
  const float* tdW1  = (const float*)d_in[9];
  const float* tdb1  = (const float*)d_in[10];
  const float* tdW2  = (const float*)d_in[11];
  const float* tdb2  = (const float*)d_in[12];

  float* ws = (float*)d_ws;
  const size_t LV = (size_t)8 * 6 * 256 * 512;   // 6,291,456 floats
  float* lv     = ws;
  float* tokens = lv + LV;                        // 1,048,576
  float* accum  = tokens + 1048576ull;            // 6,291,456
  short* W1all  = (short*)(accum + LV);           // 20,971,520 shorts
  short* W2all  = W1all + 20971520ull;            // 20,971,520 shorts
  short* Apk    = W2all + 20971520ull;            // 20,971,520 shorts
  short* hall   = Apk + 20971520ull;              // 41,943,040 shorts (5z hi/lo)
  // total = 264,241,152 B <= 264,290,304 B proven to fit (round 3)

  // attnb aliases hall's upper half (12.6 MB needed, 42 MB available);
  // it lives only between attn_k and cons_k, and hall is rewritten by the
  // NEXT iteration's ff1 passes after cons_k has consumed it.
  float* attnb = (float*)(hall + 20971520ull);
  float* dout  = (float*)d_out;

  pack_w<<<2560, 256, 0, stream>>>(buW1, W1all, 16, 16);
  pack_w<<<2560, 256, 0, stream>>>(tdW1, W1all + 5 * SH_W_GRP, 16, 16);
  pack_w<<<2560, 256, 0, stream>>>(buW2, W2all, 64, 4);
  pack_w<<<2560, 256, 0, stream>>>(tdW2, W2all + 5 * SH_W_GRP, 64, 4);

  patch_embed<<<2048, 256, 0, stream>>>(img, Wp, bp, tokens);
  init_lv_kernel<<<6144, 256, 0, stream>>>(initl, lv);
  pack_A<<<1280, 256, 0, stream>>>(lv, pos, Apk, Apk + SH_A_TDOFF);

  for (int it = 0; it < 12; ++it) {
    // K1: ff1-bu (fills hall)
    ff1_k<<<1280, 256, 0, stream>>>(W1all, Apk, bub1, hall);
    // K2: ff2-bu emode0 (store accum = lv + v, levels 1..5)
    mfma_ff2<<<640, 256, 0, stream>>>(hall, W2all, bub2, lv, tokens, accum, 1, 0);
    // K3: ff1-td (refills hall)
    ff1_k<<<1280, 256, 0, stream>>>(W1all + 5 * SH_W_GRP, Apk + SH_A_TDOFF,
                                    tdb1, hall);
    // K4: ff2-td emode1 (level0 store lv+tokens+v; levels 1..4 RMW)
    mfma_ff2<<<640, 256, 0, stream>>>(hall, W2all + 5 * SH_W_GRP, tdb2, lv,
                                      tokens, accum, 0, 1);
    // K5: attention (writes attnb over hall's upper half — hall is dead)
    attn_k<<<384, 256, 0, stream>>>(lv, attnb);
    // K6: consensus RMW into accum
    cons_k<<<768, 256, 0, stream>>>(attnb, lv, accum);
    // K7: combine + dout + next-iter A-pack
    combine3<<<3072, 256, 0, stream>>>(accum, pos, lv, Apk, Apk + SH_A_TDOFF,
                                       dout, it == 11 ? 1 : 0);
  }
}

// Round 4
// 5458.002 us; speedup vs baseline: 1.0019x; 1.0019x over previous
//
#include <hip/hip_runtime.h>
#include <math.h>

// Problem constants: B=8, S=224, P=14, D=512, L=6, NPS=16, N=256, G=5, H=2048, iters=12
#define L6 6

typedef __attribute__((ext_vector_type(8))) short bf16x8;   // 8 bf16 in 4 VGPRs
typedef __attribute__((ext_vector_type(4))) float f32x4;    // MFMA accum

#define SH_W_GRP   2097152ull   // 512*2048 hi/lo bf16 (both W1 and W2)
#define SH_A_GRP   2097152ull   // 2048 tok * 512 d hi/lo
#define SH_A_TDOFF 10485760ull  // Atd offset inside Apk (5 groups)

// Exact gelu (erff): r10-proven epilogue.
__device__ __forceinline__ float gelu_exact(float x) {
  return 0.5f * x * (1.0f + erff(x * 0.70710678118654752f));
}

__device__ __forceinline__ unsigned short bf16_rn(float x) {
  unsigned u = __float_as_uint(x);
  unsigned r = u + 0x7FFFu + ((u >> 16) & 1u);
  return (unsigned short)(r >> 16);
}
__device__ __forceinline__ float bf16_f(unsigned short h) {
  return __uint_as_float(((unsigned)h) << 16);
}
__device__ __forceinline__ void split2(float x, unsigned short* h, unsigned short* l) {
  unsigned short hh = bf16_rn(x);
  *h = hh;
  *l = bf16_rn(x - bf16_f(hh));
}
__device__ __forceinline__ int4 pack8(const unsigned short* v) {
  return make_int4((int)((unsigned)v[0] | ((unsigned)v[1] << 16)),
                   (int)((unsigned)v[2] | ((unsigned)v[3] << 16)),
                   (int)((unsigned)v[4] | ((unsigned)v[5] << 16)),
                   (int)((unsigned)v[6] | ((unsigned)v[7] << 16)));
}

__device__ __forceinline__ void gload16(const void* g, void* l) {
  __builtin_amdgcn_global_load_lds(
      (const __attribute__((address_space(1))) void*)g,
      (__attribute__((address_space(3))) void*)l, 16, 0, 0);
}

// ---------------------------------------------------------------------------
// Patch embedding
// ---------------------------------------------------------------------------
__global__ __launch_bounds__(256) void patch_embed(
    const float* __restrict__ img, const float* __restrict__ Wp,
    const float* __restrict__ bp, float* __restrict__ tokens)
{
  __shared__ float xs[588];
  const int bn = blockIdx.x;
  const int b = bn >> 8, n = bn & 255;
  const int i = n >> 4, j = n & 15;
  for (int k = threadIdx.x; k < 588; k += 256) {
    int c = k % 3;
    int t = k / 3;
    int pc = t % 14;
    int pr = t / 14;
    xs[k] = img[(((size_t)(b * 3 + c) * 224) + (i * 14 + pr)) * 224 + (j * 14 + pc)];
  }
  __syncthreads();
  const int d0 = threadIdx.x, d1 = threadIdx.x + 256;
  float a0 = 0.f, a1 = 0.f;
  for (int k = 0; k < 588; ++k) {
    float x = xs[k];
    a0 = fmaf(x, Wp[(size_t)k * 512 + d0], a0);
    a1 = fmaf(x, Wp[(size_t)k * 512 + d1], a1);
  }
  tokens[(size_t)bn * 512 + d0] = a0 + bp[d0];
  tokens[(size_t)bn * 512 + d1] = a1 + bp[d1];
}

// ---------------------------------------------------------------------------
// r4: also initializes accum = lv (+tokens at l==0) for the additive-accum
// scheme (iteration 0's base; steady-state base written by combine3).
// ---------------------------------------------------------------------------
__global__ __launch_bounds__(256) void init_lv_kernel(
    const float* __restrict__ initl, const float* __restrict__ tokens,
    float* __restrict__ lv, float* __restrict__ accum)
{
  int f = blockIdx.x * 256 + threadIdx.x;
  int d4 = f & 127;
  int n = (f >> 7) & 255;
  int vb = f >> 15;
  int l = vb % 6, b = vb / 6;
  float4 v = *(const float4*)(initl + (size_t)l * 512 + d4 * 4);
  *(float4*)(lv + (size_t)f * 4) = v;
  float4 a = v;
  if (l == 0) {
    int m = (b << 8) | n;
    float4 tv = *(const float4*)(tokens + (size_t)m * 512 + d4 * 4);
    a.x += tv.x; a.y += tv.y; a.z += tv.z; a.w += tv.w;
  }
  *(float4*)(accum + (size_t)f * 4) = a;
}

// ---------------------------------------------------------------------------
// Pack weights fp32 [G][K][N] -> hi/lo bf16 fragment-image.
// ---------------------------------------------------------------------------
__global__ __launch_bounds__(256) void pack_w(
    const float* __restrict__ src, short* __restrict__ dst, int KT, int NT)
{
  int sidx = blockIdx.x * 256 + threadIdx.x;
  int slot = sidx & 511;
  int blk = sidx >> 9;
  int kt = blk % KT;
  int rest = blk / KT;
  int nt = rest % NT;
  int g = rest / NT;
  int f = slot >> 6, lane = slot & 63;
  int N = NT * 128, K = KT * 32;
  int n = nt * 128 + f * 16 + (lane & 15);
  int k0 = kt * 32 + (lane >> 4) * 8;
  const float* s = src + ((size_t)g * K + k0) * N + n;
  unsigned short hi[8], lo[8];
#pragma unroll
  for (int j = 0; j < 8; ++j) split2(s[(size_t)j * N], &hi[j], &lo[j]);
  short* d = dst + (size_t)blk * 8192 + slot * 8;
  *(int4*)d = pack8(hi);
  *(int4*)(d + 4096) = pack8(lo);
}

// ---------------------------------------------------------------------------
// Startup A-pack (steady-state fused into combine3).
// ---------------------------------------------------------------------------
__global__ __launch_bounds__(256) void pack_A(
    const float* __restrict__ lv, const float* __restrict__ pos,
    short* __restrict__ Abu, short* __restrict__ Atd)
{
  const int bx = blockIdx.x;              // 0..1279
  const int lg = bx >> 8, mt = (bx >> 4) & 15, kt = bx & 15;
  const size_t blk = (size_t)bx * 8192;
#pragma unroll
  for (int ss = 0; ss < 2; ++ss) {
    int s = threadIdx.x + ss * 256;
    int f = s >> 6, l = s & 63;
    int m = mt * 128 + (f << 4) + (l & 15);
    int b = m >> 8, n = m & 255;
    int d = kt * 32 + ((l >> 4) << 3);
    const float* pbu = lv + ((size_t)(b * L6 + lg) * 256 + n) * 512 + d;
    const float* ptd = lv + ((size_t)(b * L6 + lg + 1) * 256 + n) * 512 + d;
    const float* pp = pos + (size_t)n * 512 + d;
    float4 u0 = *(const float4*)pbu;
    float4 u1 = *(const float4*)(pbu + 4);
    float xv[8] = {u0.x, u0.y, u0.z, u0.w, u1.x, u1.y, u1.z, u1.w};
    unsigned short hi[8], lo[8];
#pragma unroll
    for (int j = 0; j < 8; ++j) split2(xv[j], &hi[j], &lo[j]);
    *(int4*)(Abu + blk + s * 8) = pack8(hi);
    *(int4*)(Abu + blk + 4096 + s * 8) = pack8(lo);
    float4 v0 = *(const float4*)ptd;
    float4 v1 = *(const float4*)(ptd + 4);
    float4 p0 = *(const float4*)pp;
    float4 p1 = *(const float4*)(pp + 4);
    float yv[8] = {v0.x + p0.x, v0.y + p0.y, v0.z + p0.z, v0.w + p0.w,
                   v1.x + p1.x, v1.y + p1.y, v1.z + p1.z, v1.w + p1.w};
#pragma unroll
    for (int j = 0; j < 8; ++j) split2(yv[j], &hi[j], &lo[j]);
    *(int4*)(Atd + blk + s * 8) = pack8(hi);
    *(int4*)(Atd + blk + 4096 + s * 8) = pack8(lo);
  }
}

// ---------------------------------------------------------------------------
// FF1: h^T = W1^T @ lv^T, bf16x2, 128x128 block, single-buf LDS 32KB.
// r2-proven config (110us, MfmaUtil 23%, occ 33%): launch_bounds(256,3),
// product passes (hh,lh,hl) over j-pairs. r1/r3 pipelining variants both
// regressed (occupancy loss > latency win) — do not re-add.
// ---------------------------------------------------------------------------
__global__ __launch_bounds__(256, 3) void ff1_k(
    const short* __restrict__ Wa, const short* __restrict__ Ap,
    const float* __restrict__ b1, short* __restrict__ hpk)
{
  __shared__ __align__(16) short SA[8192];
  __shared__ __align__(16) short SB[8192];
  const int per_x = gridDim.x >> 3;
  const int gid = (blockIdx.x & 7) * per_x + (blockIdx.x >> 3);
  const int tt = gid & 15;
  const int tile = gid >> 4;
  const int ht = tile & 15;
  const int z = tile >> 4;
  const int tid = threadIdx.x, lane = tid & 63, w = tid >> 6;
  const int wm = (w >> 1) * 64, wn = (w & 1) * 64;
  const short* ga = Wa + (size_t)(z * 16 + ht) * 16 * 8192;
  const short* gb = Ap + (size_t)(z * 16 + tt) * 16 * 8192;
  const int soff = w * 4096 + lane * 16;

  f32x4 acc[4][4];
#pragma unroll
  for (int i = 0; i < 4; ++i)
#pragma unroll
    for (int j = 0; j < 4; ++j) acc[i][j] = (f32x4)(0.0f);

  for (int kt = 0; kt < 16; ++kt) {
    __syncthreads();
    const char* pa = (const char*)(ga + (size_t)kt * 8192);
    const char* pb = (const char*)(gb + (size_t)kt * 8192);
#pragma unroll
    for (int c = 0; c < 4; ++c) {
      gload16(pa + soff + c * 1024, (char*)SA + w * 4096 + c * 1024);
      gload16(pb + soff + c * 1024, (char*)SB + w * 4096 + c * 1024);
    }
    __syncthreads();
    bf16x8 ah[4], al[4];
#pragma unroll
    for (int i = 0; i < 4; ++i) {
      int f = (wm >> 4) + i;
      ah[i] = *(const bf16x8*)&SA[f * 512 + lane * 8];
      al[i] = *(const bf16x8*)&SA[4096 + f * 512 + lane * 8];
    }
#pragma unroll
    for (int jp = 0; jp < 2; ++jp) {
      bf16x8 bh[2], bl[2];
#pragma unroll
      for (int j2 = 0; j2 < 2; ++j2) {
        int f = (wn >> 4) + jp * 2 + j2;
        bh[j2] = *(const bf16x8*)&SB[f * 512 + lane * 8];
        bl[j2] = *(const bf16x8*)&SB[4096 + f * 512 + lane * 8];
      }
      // pass 1: A_hi * B_hi (8 independent MFMAs)
#pragma unroll
      for (int j2 = 0; j2 < 2; ++j2)
#pragma unroll
        for (int i = 0; i < 4; ++i)
          acc[i][jp * 2 + j2] = __builtin_amdgcn_mfma_f32_16x16x32_bf16(
              ah[i], bh[j2], acc[i][jp * 2 + j2], 0, 0, 0);
      // pass 2: A_lo * B_hi
#pragma unroll
      for (int j2 = 0; j2 < 2; ++j2)
#pragma unroll
        for (int i = 0; i < 4; ++i)
          acc[i][jp * 2 + j2] = __builtin_amdgcn_mfma_f32_16x16x32_bf16(
              al[i], bh[j2], acc[i][jp * 2 + j2], 0, 0, 0);
      // pass 3: A_hi * B_lo
#pragma unroll
      for (int j2 = 0; j2 < 2; ++j2)
#pragma unroll
        for (int i = 0; i < 4; ++i)
          acc[i][jp * 2 + j2] = __builtin_amdgcn_mfma_f32_16x16x32_bf16(
              ah[i], bl[j2], acc[i][jp * 2 + j2], 0, 0, 0);
    }
  }

  const int q = lane >> 4, t = lane & 15;
  const float* b1g = b1 + (size_t)z * 2048;
#pragma unroll
  for (int i = 0; i < 4; ++i) {
    int Hb = ht * 128 + wm + i * 16 + q * 4;
    float4 bv = *(const float4*)(b1g + Hb);
    float bb[4] = {bv.x, bv.y, bv.z, bv.w};
    int kt2 = Hb >> 5;
    int g2 = (Hb >> 3) & 3;
    int jb = Hb & 7;                       // 0 or 4
    size_t blkbase = ((size_t)(z * 16 + tt) * 64 + kt2) * 8192;
#pragma unroll
    for (int j = 0; j < 4; ++j) {
      int f2 = (wn >> 4) + j;
      size_t off = blkbase + (size_t)(f2 * 64 + g2 * 16 + t) * 8 + jb;
      unsigned short hi[4], lo[4];
#pragma unroll
      for (int r = 0; r < 4; ++r) {
        float x = gelu_exact(acc[i][j][r] + bb[r]);
        split2(x, &hi[r], &lo[r]);
      }
      *(uint2*)(hpk + off) =
          make_uint2((unsigned)hi[0] | ((unsigned)hi[1] << 16),
                     (unsigned)hi[2] | ((unsigned)hi[3] << 16));
      *(uint2*)(hpk + off + 4096) =
          make_uint2((unsigned)lo[0] | ((unsigned)lo[1] << 16),
                     (unsigned)lo[2] | ((unsigned)lo[3] << 16));
    }
  }
}

// ---------------------------------------------------------------------------
// Attention + fused norm + softmax -> attnb. Grid 384, XCD-grouped by bl.
// ---------------------------------------------------------------------------
__global__ __launch_bounds__(256) void attn_k(
    const float* __restrict__ lv, float* __restrict__ attnb)
{
  __shared__ __align__(16) char smemraw[38560];
  const int a = blockIdx.x;
  const int s = a >> 3;
  const int bl = (a & 7) * 6 + (s >> 3);
  const int i0 = (s & 7) * 32;
  const float* base = lv + (size_t)bl * 131072;
  float (*Al)[36] = (float(*)[36])smemraw;
  float (*Bst)[257] = (float(*)[257])(smemraw + 4608);
  float* scL = (float*)(smemraw + 4608 + 32896);
  const int tid = threadIdx.x;
  const int ty = tid >> 5, tx = tid & 31;
  float acc[4][8];
#pragma unroll
  for (int i = 0; i < 4; ++i)
#pragma unroll
    for (int j = 0; j < 8; ++j) acc[i][j] = 0.f;
  float ss[8] = {0.f, 0.f, 0.f, 0.f, 0.f, 0.f, 0.f, 0.f};

  for (int k0 = 0; k0 < 512; k0 += 32) {
    {
      int r = tid >> 3, c4 = tid & 7;
      float4 v = *(const float4*)(base + (size_t)(i0 + r) * 512 + k0 + c4 * 4);
      *(float4*)&Al[r][c4 * 4] = v;
    }
#pragma unroll
    for (int it = 0; it < 8; ++it) {
      int f = it * 256 + tid;
      int j = f >> 3, c4 = f & 7;
      float4 v = *(const float4*)(base + (size_t)j * 512 + k0 + c4 * 4);
      Bst[c4 * 4 + 0][j] = v.x;
      Bst[c4 * 4 + 1][j] = v.y;
      Bst[c4 * 4 + 2][j] = v.z;
      Bst[c4 * 4 + 3][j] = v.w;
      ss[it] += v.x * v.x + v.y * v.y + v.z * v.z + v.w * v.w;
    }
    __syncthreads();
#pragma unroll
    for (int kq = 0; kq < 8; ++kq) {
      float4 av4[4];
#pragma unroll
      for (int i = 0; i < 4; ++i) av4[i] = *(const float4*)&Al[ty * 4 + i][kq * 4];
      float av[4][4] = {{av4[0].x, av4[1].x, av4[2].x, av4[3].x},
                        {av4[0].y, av4[1].y, av4[2].y, av4[3].y},
                        {av4[0].z, av4[1].z, av4[2].z, av4[3].z},
                        {av4[0].w, av4[1].w, av4[2].w, av4[3].w}};
#pragma unroll
      for (int c = 0; c < 4; ++c) {
        float bb[8];
#pragma unroll
        for (int j = 0; j < 8; ++j) bb[j] = Bst[kq * 4 + c][tx + j * 32];
#pragma unroll
        for (int i = 0; i < 4; ++i)
#pragma unroll
          for (int j = 0; j < 8; ++j)
            acc[i][j] = fmaf(av[c][i], bb[j], acc[i][j]);
      }
    }
    __syncthreads();
  }

#pragma unroll
  for (int it = 0; it < 8; ++it) {
    float sv = ss[it];
    sv += __shfl_xor(sv, 1);
    sv += __shfl_xor(sv, 2);
    sv += __shfl_xor(sv, 4);
    if ((tid & 7) == 0) scL[(it * 256 + tid) >> 3] = 1.0f / fmaxf(sqrtf(sv), 1e-12f);
  }
  __syncthreads();

  const float rs = 0.04419417382415922f;  // 512^-0.5
#pragma unroll
  for (int ii = 0; ii < 4; ++ii) {
    int i = i0 + ty * 4 + ii;
    float v[8];
    float mx = -1e30f;
#pragma unroll
    for (int jj = 0; jj < 8; ++jj) {
      int j = tx + jj * 32;
      float sv = acc[ii][jj] * scL[j] * rs;
      if (j == i) sv = -0.0005f;
      v[jj] = sv;
      mx = fmaxf(mx, sv);
    }
#pragma unroll
    for (int o = 1; o < 32; o <<= 1) mx = fmaxf(mx, __shfl_xor(mx, o));
    float sum = 0.f;
#pragma unroll
    for (int jj = 0; jj < 8; ++jj) {
      v[jj] = expf(v[jj] - mx);
      sum += v[jj];
    }
#pragma unroll
    for (int o = 1; o < 32; o <<= 1) sum += __shfl_xor(sum, o);
    float inv = 1.0f / sum;
    float* orow = attnb + (size_t)bl * 65536 + (size_t)i * 256;
#pragma unroll
    for (int jj = 0; jj < 8; ++jj) orow[tx + jj * 32] = v[jj] * inv;
  }
}

// ---------------------------------------------------------------------------
// Consensus: accum += attnb @ lv (pure RMW). Grid 768, XCD-grouped by bl.
// ---------------------------------------------------------------------------
__global__ __launch_bounds__(256) void cons_k(
    const float* __restrict__ attnb, const float* __restrict__ lv,
    float* __restrict__ accum)
{
  __shared__ __align__(16) char smemraw[25088];
  const int a = blockIdx.x;
  const int s = a >> 3;
  const int bl = (a & 7) * 6 + (s >> 4);
  const int tile = s & 15;
  int it0 = (tile >> 2) * 64;
  int dt0 = (tile & 3) * 128;
  const float* A = attnb + (size_t)bl * 65536;
  const float* Bm = lv + (size_t)bl * 131072;
  float (*Ast)[68] = (float(*)[68])smemraw;
  float (*Bs)[128] = (float(*)[128])(smemraw + 8704);
  const int tid = threadIdx.x;
  const int ty = tid >> 4, tx = tid & 15;
  float acc[4][8];
#pragma unroll
  for (int i = 0; i < 4; ++i)
#pragma unroll
    for (int j = 0; j < 8; ++j) acc[i][j] = 0.f;

  for (int k0 = 0; k0 < 256; k0 += 32) {
#pragma unroll
    for (int it = 0; it < 2; ++it) {
      int f = it * 256 + tid;
      int r = f >> 3, c4 = f & 7;
      float4 v = *(const float4*)(A + (size_t)(it0 + r) * 256 + k0 + c4 * 4);
      Ast[c4 * 4 + 0][r] = v.x;
      Ast[c4 * 4 + 1][r] = v.y;
      Ast[c4 * 4 + 2][r] = v.z;
      Ast[c4 * 4 + 3][r] = v.w;
    }
#pragma unroll
    for (int it = 0; it < 4; ++it) {
      int kr = (tid >> 5) + it * 8;
      int c4 = tid & 31;
      *(float4*)&Bs[kr][c4 * 4] =
          *(const float4*)(Bm + (size_t)(k0 + kr) * 512 + dt0 + c4 * 4);
    }
    __syncthreads();
#pragma unroll 8
    for (int k = 0; k < 32; ++k) {
      float4 av = *(const float4*)&Ast[k][ty * 4];
      float4 b0 = *(const float4*)&Bs[k][tx * 4];
      float4 b1 = *(const float4*)&Bs[k][64 + tx * 4];
      float avv[4] = {av.x, av.y, av.z, av.w};
      float bv[8] = {b0.x, b0.y, b0.z, b0.w, b1.x, b1.y, b1.z, b1.w};
#pragma unroll
      for (int i = 0; i < 4; ++i)
#pragma unroll
        for (int j = 0; j < 8; ++j)
          acc[i][j] = fmaf(avv[i], bv[j], acc[i][j]);
    }
    __syncthreads();
  }
#pragma unroll
  for (int ii = 0; ii < 4; ++ii) {
    int i = it0 + ty * 4 + ii;
    float* arow = accum + (size_t)bl * 131072 + (size_t)i * 512 + dt0;
#pragma unroll
    for (int j = 0; j < 4; ++j) arow[tx * 4 + j] += acc[ii][j];
#pragma unroll
    for (int j = 0; j < 4; ++j) arow[64 + tx * 4 + j] += acc[ii][4 + j];
  }
}

// ---------------------------------------------------------------------------
// FF2: 64(token) x 128(outd) block. r4: K=2048 split into 2 halves of 1024
// (grid 640 -> 1280 = 5 blocks/CU, TLP parity with ff1). Additive-accum:
// epilogue is pure atomicAdd onto accum (pre-initialized with lv(+tokens)
// by combine3/init_lv). Bias b2 added only by the h==0 half. Per-step LDS
// volume/ratios unchanged; per-block K-steps 64 -> 32.
// ---------------------------------------------------------------------------
__global__ __launch_bounds__(256, 4) void mfma_ff2(
    const short* __restrict__ hpk, const short* __restrict__ Wb,
    const float* __restrict__ b2, float* accum, int olvbase)
{
  const int per_x = gridDim.x >> 3;    // 160
  const int gid = (blockIdx.x & 7) * per_x + (blockIdx.x >> 3);
  const int nt2 = gid & 3;
  const int mt2 = (gid >> 2) & 31;     // 64-token tiles
  const int zh = gid >> 7;             // 0..9
  const int h = (zh >= 5) ? 1 : 0;     // K-half
  const int z = zh - h * 5;

  __shared__ __align__(16) short SA[4096];   // hi 2048 | lo 2048
  __shared__ __align__(16) short SB[8192];   // hi 4096 | lo 4096
  const int tid = threadIdx.x, lane = tid & 63, w = tid >> 6;
  const int wm = (w >> 1) * 32, wn = (w & 1) * 64;
  const short* gaBase = hpk + (size_t)(z * 16 + (mt2 >> 1)) * 64 * 8192
                        + (size_t)(mt2 & 1) * 2048
                        + (size_t)h * 32 * 8192;
  const short* gb = Wb + (size_t)(z * 4 + nt2) * 64 * 8192
                    + (size_t)h * 32 * 8192;

  f32x4 acc[2][4];
#pragma unroll
  for (int i = 0; i < 2; ++i)
#pragma unroll
    for (int j = 0; j < 4; ++j) acc[i][j] = (f32x4)(0.0f);

  for (int kt = 0; kt < 32; ++kt) {
    __syncthreads();
    const char* pa = (const char*)(gaBase + (size_t)kt * 8192);
    const char* pb = (const char*)(gb + (size_t)kt * 8192);
    gload16(pa + w * 1024 + lane * 16, (char*)SA + w * 1024);
    gload16(pa + 8192 + w * 1024 + lane * 16, (char*)SA + 4096 + w * 1024);
#pragma unroll
    for (int c = 0; c < 4; ++c)
      gload16(pb + w * 4096 + c * 1024 + lane * 16,
              (char*)SB + w * 4096 + c * 1024);
    __syncthreads();
    bf16x8 ah[2], al[2];
#pragma unroll
    for (int i = 0; i < 2; ++i) {
      int f = (wm >> 4) + i;
      ah[i] = *(const bf16x8*)&SA[f * 512 + lane * 8];
      al[i] = *(const bf16x8*)&SA[2048 + f * 512 + lane * 8];
    }
#pragma unroll
    for (int jp = 0; jp < 2; ++jp) {
      bf16x8 bh[2], bl[2];
#pragma unroll
      for (int j2 = 0; j2 < 2; ++j2) {
        int f = (wn >> 4) + jp * 2 + j2;
        bh[j2] = *(const bf16x8*)&SB[f * 512 + lane * 8];
        bl[j2] = *(const bf16x8*)&SB[4096 + f * 512 + lane * 8];
      }
#pragma unroll
      for (int j2 = 0; j2 < 2; ++j2)
#pragma unroll
        for (int i = 0; i < 2; ++i)
          acc[i][jp * 2 + j2] = __builtin_amdgcn_mfma_f32_16x16x32_bf16(
              ah[i], bh[j2], acc[i][jp * 2 + j2], 0, 0, 0);
#pragma unroll
      for (int j2 = 0; j2 < 2; ++j2)
#pragma unroll
        for (int i = 0; i < 2; ++i)
          acc[i][jp * 2 + j2] = __builtin_amdgcn_mfma_f32_16x16x32_bf16(
              al[i], bh[j2], acc[i][jp * 2 + j2], 0, 0, 0);
#pragma unroll
      for (int j2 = 0; j2 < 2; ++j2)
#pragma unroll
        for (int i = 0; i < 2; ++i)
          acc[i][jp * 2 + j2] = __builtin_amdgcn_mfma_f32_16x16x32_bf16(
              ah[i], bl[j2], acc[i][jp * 2 + j2], 0, 0, 0);
    }
  }

  const int q = lane >> 4, t = lane & 15;
  const float* b2g = b2 + (size_t)z * 512;
  const int level = olvbase + z;
#pragma unroll
  for (int i = 0; i < 2; ++i) {
#pragma unroll
    for (int r = 0; r < 4; ++r) {
      int m = mt2 * 64 + wm + i * 16 + q * 4 + r;
      int b = m >> 8, n = m & 255;
      size_t rowoff = ((size_t)(b * L6 + level) * 256 + n) * 512;
      float* arow = accum + rowoff;
#pragma unroll
      for (int j = 0; j < 4; ++j) {
        int col = nt2 * 128 + wn + j * 16 + t;
        float v = acc[i][j][r] + (h == 0 ? b2g[col] : 0.0f);
        atomicAdd(arow + col, v);
      }
    }
  }
}

// ---------------------------------------------------------------------------
// combine3: lv = accum/contrib, write dout on last iter, fused next-iter
// A-packing, and (r4) re-initialize accum = lv (+tokens at l==0) as the
// additive base for next iteration's ff2/cons adds. Grid 3072.
// ---------------------------------------------------------------------------
__global__ __launch_bounds__(256) void combine3(
    float* accum, const float* __restrict__ pos,
    const float* __restrict__ tokens, float* __restrict__ lv_out,
    short* __restrict__ Abu, short* __restrict__ Atd,
    float* __restrict__ dout, int last)
{
  int t = blockIdx.x * 256 + threadIdx.x;   // 786,432 total
  int d8 = t & 63;
  int n = (t >> 6) & 255;
  int v = t >> 14;                          // b*6 + l, 0..47
  int l = v % 6, b = v / 6;
  int bn = (b << 8) | n;
  size_t idx = ((size_t)v * 256 + n) * 512 + d8 * 8;
  float4 a0 = *(const float4*)(accum + idx);
  float4 a1 = *(const float4*)(accum + idx + 4);
  float sc = (l == 5) ? (1.0f / 3.0f) : 0.25f;
  float r[8];
  r[0] = a0.x * sc; r[1] = a0.y * sc; r[2] = a0.z * sc; r[3] = a0.w * sc;
  r[4] = a1.x * sc; r[5] = a1.y * sc; r[6] = a1.z * sc; r[7] = a1.w * sc;
  *(float4*)(lv_out + idx) = make_float4(r[0], r[1], r[2], r[3]);
  *(float4*)(lv_out + idx + 4) = make_float4(r[4], r[5], r[6], r[7]);
  if (last) {
    float* dp = dout + ((size_t)bn * 6 + l) * 512 + d8 * 8;
    *(float4*)dp = make_float4(r[0], r[1], r[2], r[3]);
    *(float4*)(dp + 4) = make_float4(r[4], r[5], r[6], r[7]);
  }
  // re-init accum base for next iteration (additive scheme)
  {
    float a[8] = {r[0], r[1], r[2], r[3], r[4], r[5], r[6], r[7]};
    if (l == 0) {
      const float* tp = tokens + (size_t)bn * 512 + d8 * 8;
      float4 t0 = *(const float4*)tp;
      float4 t1 = *(const float4*)(tp + 4);
      a[0] += t0.x; a[1] += t0.y; a[2] += t0.z; a[3] += t0.w;
      a[4] += t1.x; a[5] += t1.y; a[6] += t1.z; a[7] += t1.w;
    }
    *(float4*)(accum + idx) = make_float4(a[0], a[1], a[2], a[3]);
    *(float4*)(accum + idx + 4) = make_float4(a[4], a[5], a[6], a[7]);
  }
  int m = bn;
  int mt = m >> 7;
  int kt = d8 >> 2;
  int s = (((m & 127) >> 4) << 6) | (((d8 & 3) << 4) | (m & 15));
  unsigned short hi[8], lo[8];
  if (l < 5) {
    size_t blk = ((size_t)(l * 16 + mt) * 16 + kt) * 8192;
#pragma unroll
    for (int j = 0; j < 8; ++j) split2(r[j], &hi[j], &lo[j]);
    *(int4*)(Abu + blk + s * 8) = pack8(hi);
    *(int4*)(Abu + blk + 4096 + s * 8) = pack8(lo);
  }
  if (l >= 1) {
    const float* pp = pos + (size_t)n * 512 + d8 * 8;
    float4 p0 = *(const float4*)pp;
    float4 p1 = *(const float4*)(pp + 4);
    float y[8] = {r[0] + p0.x, r[1] + p0.y, r[2] + p0.z, r[3] + p0.w,
                  r[4] + p1.x, r[5] + p1.y, r[6] + p1.z, r[7] + p1.w};
    size_t blk = ((size_t)((l - 1) * 16 + mt) * 16 + kt) * 8192;
#pragma unroll
    for (int j = 0; j < 8; ++j) split2(y[j], &hi[j], &lo[j]);
    *(int4*)(Atd + blk + s * 8) = pack8(hi);
    *(int4*)(Atd + blk + 4096 + s * 8) = pack8(lo);
  }
}

// ---------------------------------------------------------------------------
extern "C" void kernel_launch(void* const* d_in, const int* in_sizes, int n_in,
                              void* d_out, int out_size, void* d_ws, size_t ws_size,
                              hipStream_t stream)
{
  const float* img   = (const float*)d_in[0];
  const float* Wp    = (const float*)d_in[1];
  const float* bp    = (const float*)d_in[2];
  const float* pos   = (const float*)d_in[3];
  const float* initl = (const float*)d_in[4];
  const float* buW1  = (const float*)d_in[5];
  const float* bub1  = (const float*)d_in[6];
  const float* buW2  = (const float*)d_in[7];
  const float* bub2  = (const float*)d_in[8];
  const float* tdW1  = (const float*)d_in[9];
  const float* tdb1  = (const float*)d_in[10];
  const float* tdW2  = (const float*)d_in[11];
  const float* tdb2  = (const float*)d_in[12];

  float* ws = (float*)d_ws;
  const size_t LV = (size_t)8 * 6 * 256 * 512;   // 6,291,456 floats
  float* lv     = ws;
  float* tokens = lv + LV;                        // 1,048,576
  float* accum  = tokens + 1048576ull;            // 6,291,456
  short* W1all  = (short*)(accum + LV);           // 20,971,520 shorts
  short* W2all  = W1all + 20971520ull;            // 20,971,520 shorts
  short* Apk    = W2all + 20971520ull;            // 20,971,520 shorts
  short* hall   = Apk + 20971520ull;              // 41,943,040 shorts (5z hi/lo)
  // total = 264,241,152 B <= 264,290,304 B proven to fit (round 3)

  // attnb aliases hall's upper half (12.6 MB needed, 42 MB available);
  // it lives only between attn_k and cons_k, and hall is rewritten by the
  // NEXT iteration's ff1 passes after cons_k has consumed it.
  float* attnb = (float*)(hall + 20971520ull);
  float* dout  = (float*)d_out;

  pack_w<<<2560, 256, 0, stream>>>(buW1, W1all, 16, 16);
  pack_w<<<2560, 256, 0, stream>>>(tdW1, W1all + 5 * SH_W_GRP, 16, 16);
  pack_w<<<2560, 256, 0, stream>>>(buW2, W2all, 64, 4);
  pack_w<<<2560, 256, 0, stream>>>(tdW2, W2all + 5 * SH_W_GRP, 64, 4);

  patch_embed<<<2048, 256, 0, stream>>>(img, Wp, bp, tokens);
  init_lv_kernel<<<6144, 256, 0, stream>>>(initl, tokens, lv, accum);
  pack_A<<<1280, 256, 0, stream>>>(lv, pos, Apk, Apk + SH_A_TDOFF);

  for (int it = 0; it < 12; ++it) {
    // K1: ff1-bu (fills hall)
    ff1_k<<<1280, 256, 0, stream>>>(W1all, Apk, bub1, hall);
    // K2: ff2-bu (atomicAdd v_bu onto accum base, levels 1..5)
    mfma_ff2<<<1280, 256, 0, stream>>>(hall, W2all, bub2, accum, 1);
    // K3: ff1-td (refills hall)
    ff1_k<<<1280, 256, 0, stream>>>(W1all + 5 * SH_W_GRP, Apk + SH_A_TDOFF,
                                    tdb1, hall);
    // K4: ff2-td (atomicAdd v_td onto accum, levels 0..4)
    mfma_ff2<<<1280, 256, 0, stream>>>(hall, W2all + 5 * SH_W_GRP, tdb2,
                                       accum, 0);
    // K5: attention (writes attnb over hall's upper half — hall is dead)
    attn_k<<<384, 256, 0, stream>>>(lv, attnb);
    // K6: consensus RMW into accum
    cons_k<<<768, 256, 0, stream>>>(attnb, lv, accum);
    // K7: combine + dout + next-iter A-pack + accum re-init
    combine3<<<3072, 256, 0, stream>>>(accum, pos, tokens, lv, Apk,
                                       Apk + SH_A_TDOFF, dout,
                                       it == 11 ? 1 : 0);
  }
}

// Round 5
// 5440.719 us; speedup vs baseline: 1.0051x; 1.0032x over previous
//
#include <hip/hip_runtime.h>
#include <math.h>

// Problem constants: B=8, S=224, P=14, D=512, L=6, NPS=16, N=256, G=5, H=2048, iters=12
#define L6 6

typedef __attribute__((ext_vector_type(8))) short bf16x8;   // 8 bf16 in 4 VGPRs
typedef __attribute__((ext_vector_type(4))) float f32x4;    // MFMA accum

#define SH_W_GRP   2097152ull   // 512*2048 hi/lo bf16 (both W1 and W2)
#define SH_A_GRP   2097152ull   // 2048 tok * 512 d hi/lo
#define SH_A_TDOFF 10485760ull  // Atd offset inside Apk (5 groups)

// Exact gelu (erff): r10-proven epilogue.
__device__ __forceinline__ float gelu_exact(float x) {
  return 0.5f * x * (1.0f + erff(x * 0.70710678118654752f));
}

__device__ __forceinline__ unsigned short bf16_rn(float x) {
  unsigned u = __float_as_uint(x);
  unsigned r = u + 0x7FFFu + ((u >> 16) & 1u);
  return (unsigned short)(r >> 16);
}
__device__ __forceinline__ float bf16_f(unsigned short h) {
  return __uint_as_float(((unsigned)h) << 16);
}
__device__ __forceinline__ void split2(float x, unsigned short* h, unsigned short* l) {
  unsigned short hh = bf16_rn(x);
  *h = hh;
  *l = bf16_rn(x - bf16_f(hh));
}
__device__ __forceinline__ int4 pack8(const unsigned short* v) {
  return make_int4((int)((unsigned)v[0] | ((unsigned)v[1] << 16)),
                   (int)((unsigned)v[2] | ((unsigned)v[3] << 16)),
                   (int)((unsigned)v[4] | ((unsigned)v[5] << 16)),
                   (int)((unsigned)v[6] | ((unsigned)v[7] << 16)));
}

__device__ __forceinline__ void gload16(const void* g, void* l) {
  __builtin_amdgcn_global_load_lds(
      (const __attribute__((address_space(1))) void*)g,
      (__attribute__((address_space(3))) void*)l, 16, 0, 0);
}

// ---------------------------------------------------------------------------
// Patch embedding
// ---------------------------------------------------------------------------
__global__ __launch_bounds__(256) void patch_embed(
    const float* __restrict__ img, const float* __restrict__ Wp,
    const float* __restrict__ bp, float* __restrict__ tokens)
{
  __shared__ float xs[588];
  const int bn = blockIdx.x;
  const int b = bn >> 8, n = bn & 255;
  const int i = n >> 4, j = n & 15;
  for (int k = threadIdx.x; k < 588; k += 256) {
    int c = k % 3;
    int t = k / 3;
    int pc = t % 14;
    int pr = t / 14;
    xs[k] = img[(((size_t)(b * 3 + c) * 224) + (i * 14 + pr)) * 224 + (j * 14 + pc)];
  }
  __syncthreads();
  const int d0 = threadIdx.x, d1 = threadIdx.x + 256;
  float a0 = 0.f, a1 = 0.f;
  for (int k = 0; k < 588; ++k) {
    float x = xs[k];
    a0 = fmaf(x, Wp[(size_t)k * 512 + d0], a0);
    a1 = fmaf(x, Wp[(size_t)k * 512 + d1], a1);
  }
  tokens[(size_t)bn * 512 + d0] = a0 + bp[d0];
  tokens[(size_t)bn * 512 + d1] = a1 + bp[d1];
}

// ---------------------------------------------------------------------------
__global__ __launch_bounds__(256) void init_lv_kernel(
    const float* __restrict__ initl, float* __restrict__ lv)
{
  int f = blockIdx.x * 256 + threadIdx.x;
  int d4 = f & 127;
  int l = (f >> 15) % 6;
  float4 v = *(const float4*)(initl + (size_t)l * 512 + d4 * 4);
  *(float4*)(lv + (size_t)f * 4) = v;
}

// ---------------------------------------------------------------------------
// Pack weights fp32 [G][K][N] -> hi/lo bf16 fragment-image.
// ---------------------------------------------------------------------------
__global__ __launch_bounds__(256) void pack_w(
    const float* __restrict__ src, short* __restrict__ dst, int KT, int NT)
{
  int sidx = blockIdx.x * 256 + threadIdx.x;
  int slot = sidx & 511;
  int blk = sidx >> 9;
  int kt = blk % KT;
  int rest = blk / KT;
  int nt = rest % NT;
  int g = rest / NT;
  int f = slot >> 6, lane = slot & 63;
  int N = NT * 128, K = KT * 32;
  int n = nt * 128 + f * 16 + (lane & 15);
  int k0 = kt * 32 + (lane >> 4) * 8;
  const float* s = src + ((size_t)g * K + k0) * N + n;
  unsigned short hi[8], lo[8];
#pragma unroll
  for (int j = 0; j < 8; ++j) split2(s[(size_t)j * N], &hi[j], &lo[j]);
  short* d = dst + (size_t)blk * 8192 + slot * 8;
  *(int4*)d = pack8(hi);
  *(int4*)(d + 4096) = pack8(lo);
}

// ---------------------------------------------------------------------------
// Startup A-pack (steady-state fused into combine3).
// ---------------------------------------------------------------------------
__global__ __launch_bounds__(256) void pack_A(
    const float* __restrict__ lv, const float* __restrict__ pos,
    short* __restrict__ Abu, short* __restrict__ Atd)
{
  const int bx = blockIdx.x;              // 0..1279
  const int lg = bx >> 8, mt = (bx >> 4) & 15, kt = bx & 15;
  const size_t blk = (size_t)bx * 8192;
#pragma unroll
  for (int ss = 0; ss < 2; ++ss) {
    int s = threadIdx.x + ss * 256;
    int f = s >> 6, l = s & 63;
    int m = mt * 128 + (f << 4) + (l & 15);
    int b = m >> 8, n = m & 255;
    int d = kt * 32 + ((l >> 4) << 3);
    const float* pbu = lv + ((size_t)(b * L6 + lg) * 256 + n) * 512 + d;
    const float* ptd = lv + ((size_t)(b * L6 + lg + 1) * 256 + n) * 512 + d;
    const float* pp = pos + (size_t)n * 512 + d;
    float4 u0 = *(const float4*)pbu;
    float4 u1 = *(const float4*)(pbu + 4);
    float xv[8] = {u0.x, u0.y, u0.z, u0.w, u1.x, u1.y, u1.z, u1.w};
    unsigned short hi[8], lo[8];
#pragma unroll
    for (int j = 0; j < 8; ++j) split2(xv[j], &hi[j], &lo[j]);
    *(int4*)(Abu + blk + s * 8) = pack8(hi);
    *(int4*)(Abu + blk + 4096 + s * 8) = pack8(lo);
    float4 v0 = *(const float4*)ptd;
    float4 v1 = *(const float4*)(ptd + 4);
    float4 p0 = *(const float4*)pp;
    float4 p1 = *(const float4*)(pp + 4);
    float yv[8] = {v0.x + p0.x, v0.y + p0.y, v0.z + p0.z, v0.w + p0.w,
                   v1.x + p1.x, v1.y + p1.y, v1.z + p1.z, v1.w + p1.w};
#pragma unroll
    for (int j = 0; j < 8; ++j) split2(yv[j], &hi[j], &lo[j]);
    *(int4*)(Atd + blk + s * 8) = pack8(hi);
    *(int4*)(Atd + blk + 4096 + s * 8) = pack8(lo);
  }
}

// ---------------------------------------------------------------------------
// FF1: h^T = W1^T @ lv^T, bf16x2, 128x128 block, single-buf LDS 32KB.
// r2-proven config (109us, MfmaUtil 24%, occ 33%): launch_bounds(256,3),
// product passes (hh,lh,hl) over j-pairs. r1/r3 pipelining variants both
// regressed (occupancy loss > latency win) — do not re-add.
// ---------------------------------------------------------------------------
__global__ __launch_bounds__(256, 3) void ff1_k(
    const short* __restrict__ Wa, const short* __restrict__ Ap,
    const float* __restrict__ b1, short* __restrict__ hpk)
{
  __shared__ __align__(16) short SA[8192];
  __shared__ __align__(16) short SB[8192];
  const int per_x = gridDim.x >> 3;
  const int gid = (blockIdx.x & 7) * per_x + (blockIdx.x >> 3);
  const int tt = gid & 15;
  const int tile = gid >> 4;
  const int ht = tile & 15;
  const int z = tile >> 4;
  const int tid = threadIdx.x, lane = tid & 63, w = tid >> 6;
  const int wm = (w >> 1) * 64, wn = (w & 1) * 64;
  const short* ga = Wa + (size_t)(z * 16 + ht) * 16 * 8192;
  const short* gb = Ap + (size_t)(z * 16 + tt) * 16 * 8192;
  const int soff = w * 4096 + lane * 16;

  f32x4 acc[4][4];
#pragma unroll
  for (int i = 0; i < 4; ++i)
#pragma unroll
    for (int j = 0; j < 4; ++j) acc[i][j] = (f32x4)(0.0f);

  for (int kt = 0; kt < 16; ++kt) {
    __syncthreads();
    const char* pa = (const char*)(ga + (size_t)kt * 8192);
    const char* pb = (const char*)(gb + (size_t)kt * 8192);
#pragma unroll
    for (int c = 0; c < 4; ++c) {
      gload16(pa + soff + c * 1024, (char*)SA + w * 4096 + c * 1024);
      gload16(pb + soff + c * 1024, (char*)SB + w * 4096 + c * 1024);
    }
    __syncthreads();
    bf16x8 ah[4], al[4];
#pragma unroll
    for (int i = 0; i < 4; ++i) {
      int f = (wm >> 4) + i;
      ah[i] = *(const bf16x8*)&SA[f * 512 + lane * 8];
      al[i] = *(const bf16x8*)&SA[4096 + f * 512 + lane * 8];
    }
#pragma unroll
    for (int jp = 0; jp < 2; ++jp) {
      bf16x8 bh[2], bl[2];
#pragma unroll
      for (int j2 = 0; j2 < 2; ++j2) {
        int f = (wn >> 4) + jp * 2 + j2;
        bh[j2] = *(const bf16x8*)&SB[f * 512 + lane * 8];
        bl[j2] = *(const bf16x8*)&SB[4096 + f * 512 + lane * 8];
      }
      // pass 1: A_hi * B_hi (8 independent MFMAs)
#pragma unroll
      for (int j2 = 0; j2 < 2; ++j2)
#pragma unroll
        for (int i = 0; i < 4; ++i)
          acc[i][jp * 2 + j2] = __builtin_amdgcn_mfma_f32_16x16x32_bf16(
              ah[i], bh[j2], acc[i][jp * 2 + j2], 0, 0, 0);
      // pass 2: A_lo * B_hi
#pragma unroll
      for (int j2 = 0; j2 < 2; ++j2)
#pragma unroll
        for (int i = 0; i < 4; ++i)
          acc[i][jp * 2 + j2] = __builtin_amdgcn_mfma_f32_16x16x32_bf16(
              al[i], bh[j2], acc[i][jp * 2 + j2], 0, 0, 0);
      // pass 3: A_hi * B_lo
#pragma unroll
      for (int j2 = 0; j2 < 2; ++j2)
#pragma unroll
        for (int i = 0; i < 4; ++i)
          acc[i][jp * 2 + j2] = __builtin_amdgcn_mfma_f32_16x16x32_bf16(
              ah[i], bl[j2], acc[i][jp * 2 + j2], 0, 0, 0);
    }
  }

  const int q = lane >> 4, t = lane & 15;
  const float* b1g = b1 + (size_t)z * 2048;
#pragma unroll
  for (int i = 0; i < 4; ++i) {
    int Hb = ht * 128 + wm + i * 16 + q * 4;
    float4 bv = *(const float4*)(b1g + Hb);
    float bb[4] = {bv.x, bv.y, bv.z, bv.w};
    int kt2 = Hb >> 5;
    int g2 = (Hb >> 3) & 3;
    int jb = Hb & 7;                       // 0 or 4
    size_t blkbase = ((size_t)(z * 16 + tt) * 64 + kt2) * 8192;
#pragma unroll
    for (int j = 0; j < 4; ++j) {
      int f2 = (wn >> 4) + j;
      size_t off = blkbase + (size_t)(f2 * 64 + g2 * 16 + t) * 8 + jb;
      unsigned short hi[4], lo[4];
#pragma unroll
      for (int r = 0; r < 4; ++r) {
        float x = gelu_exact(acc[i][j][r] + bb[r]);
        split2(x, &hi[r], &lo[r]);
      }
      *(uint2*)(hpk + off) =
          make_uint2((unsigned)hi[0] | ((unsigned)hi[1] << 16),
                     (unsigned)hi[2] | ((unsigned)hi[3] << 16));
      *(uint2*)(hpk + off + 4096) =
          make_uint2((unsigned)lo[0] | ((unsigned)lo[1] << 16),
                     (unsigned)lo[2] | ((unsigned)lo[3] << 16));
    }
  }
}

// ---------------------------------------------------------------------------
// Attention + fused norm + softmax -> attnb. r5: i-tile 32 -> 16 rows,
// grid 384 -> 768 (1.5 -> 3 blocks/CU). Per-row FMA order unchanged ->
// bit-identical; B-panel stage duplicated 2x but L2-served (HBM was 2.9%).
// XCD-grouped by bl: all 16 i-tiles of one bl share one XCD's L2.
// ---------------------------------------------------------------------------
__global__ __launch_bounds__(256) void attn_k(
    const float* __restrict__ lv, float* __restrict__ attnb)
{
  __shared__ __align__(16) char smemraw[36224];
  const int a = blockIdx.x;
  const int s = a >> 3;
  const int bl = (a & 7) * 6 + (s >> 4);
  const int i0 = (s & 15) * 16;
  const float* base = lv + (size_t)bl * 131072;
  float (*Al)[36] = (float(*)[36])smemraw;                 // 16 rows x 36
  float (*Bst)[257] = (float(*)[257])(smemraw + 2304);
  float* scL = (float*)(smemraw + 2304 + 32896);
  const int tid = threadIdx.x;
  const int ty = tid >> 5, tx = tid & 31;
  float acc[2][8];
#pragma unroll
  for (int i = 0; i < 2; ++i)
#pragma unroll
    for (int j = 0; j < 8; ++j) acc[i][j] = 0.f;
  float ss[8] = {0.f, 0.f, 0.f, 0.f, 0.f, 0.f, 0.f, 0.f};

  for (int k0 = 0; k0 < 512; k0 += 32) {
    if (tid < 128) {
      int r = tid >> 3, c4 = tid & 7;
      float4 v = *(const float4*)(base + (size_t)(i0 + r) * 512 + k0 + c4 * 4);
      *(float4*)&Al[r][c4 * 4] = v;
    }
#pragma unroll
    for (int it = 0; it < 8; ++it) {
      int f = it * 256 + tid;
      int j = f >> 3, c4 = f & 7;
      float4 v = *(const float4*)(base + (size_t)j * 512 + k0 + c4 * 4);
      Bst[c4 * 4 + 0][j] = v.x;
      Bst[c4 * 4 + 1][j] = v.y;
      Bst[c4 * 4 + 2][j] = v.z;
      Bst[c4 * 4 + 3][j] = v.w;
      ss[it] += v.x * v.x + v.y * v.y + v.z * v.z + v.w * v.w;
    }
    __syncthreads();
#pragma unroll
    for (int kq = 0; kq < 8; ++kq) {
      float4 av4[2];
#pragma unroll
      for (int i = 0; i < 2; ++i) av4[i] = *(const float4*)&Al[ty * 2 + i][kq * 4];
      float av[4][2] = {{av4[0].x, av4[1].x},
                        {av4[0].y, av4[1].y},
                        {av4[0].z, av4[1].z},
                        {av4[0].w, av4[1].w}};
#pragma unroll
      for (int c = 0; c < 4; ++c) {
        float bb[8];
#pragma unroll
        for (int j = 0; j < 8; ++j) bb[j] = Bst[kq * 4 + c][tx + j * 32];
#pragma unroll
        for (int i = 0; i < 2; ++i)
#pragma unroll
          for (int j = 0; j < 8; ++j)
            acc[i][j] = fmaf(av[c][i], bb[j], acc[i][j]);
      }
    }
    __syncthreads();
  }

#pragma unroll
  for (int it = 0; it < 8; ++it) {
    float sv = ss[it];
    sv += __shfl_xor(sv, 1);
    sv += __shfl_xor(sv, 2);
    sv += __shfl_xor(sv, 4);
    if ((tid & 7) == 0) scL[(it * 256 + tid) >> 3] = 1.0f / fmaxf(sqrtf(sv), 1e-12f);
  }
  __syncthreads();

  const float rs = 0.04419417382415922f;  // 512^-0.5
#pragma unroll
  for (int ii = 0; ii < 2; ++ii) {
    int i = i0 + ty * 2 + ii;
    float v[8];
    float mx = -1e30f;
#pragma unroll
    for (int jj = 0; jj < 8; ++jj) {
      int j = tx + jj * 32;
      float sv = acc[ii][jj] * scL[j] * rs;
      if (j == i) sv = -0.0005f;
      v[jj] = sv;
      mx = fmaxf(mx, sv);
    }
#pragma unroll
    for (int o = 1; o < 32; o <<= 1) mx = fmaxf(mx, __shfl_xor(mx, o));
    float sum = 0.f;
#pragma unroll
    for (int jj = 0; jj < 8; ++jj) {
      v[jj] = expf(v[jj] - mx);
      sum += v[jj];
    }
#pragma unroll
    for (int o = 1; o < 32; o <<= 1) sum += __shfl_xor(sum, o);
    float inv = 1.0f / sum;
    float* orow = attnb + (size_t)bl * 65536 + (size_t)i * 256;
#pragma unroll
    for (int jj = 0; jj < 8; ++jj) orow[tx + jj * 32] = v[jj] * inv;
  }
}

// ---------------------------------------------------------------------------
// Consensus: accum += attnb @ lv (pure RMW). Grid 768, XCD-grouped by bl.
// ---------------------------------------------------------------------------
__global__ __launch_bounds__(256) void cons_k(
    const float* __restrict__ attnb, const float* __restrict__ lv,
    float* __restrict__ accum)
{
  __shared__ __align__(16) char smemraw[25088];
  const int a = blockIdx.x;
  const int s = a >> 3;
  const int bl = (a & 7) * 6 + (s >> 4);
  const int tile = s & 15;
  int it0 = (tile >> 2) * 64;
  int dt0 = (tile & 3) * 128;
  const float* A = attnb + (size_t)bl * 65536;
  const float* Bm = lv + (size_t)bl * 131072;
  float (*Ast)[68] = (float(*)[68])smemraw;
  float (*Bs)[128] = (float(*)[128])(smemraw + 8704);
  const int tid = threadIdx.x;
  const int ty = tid >> 4, tx = tid & 15;
  float acc[4][8];
#pragma unroll
  for (int i = 0; i < 4; ++i)
#pragma unroll
    for (int j = 0; j < 8; ++j) acc[i][j] = 0.f;

  for (int k0 = 0; k0 < 256; k0 += 32) {
#pragma unroll
    for (int it = 0; it < 2; ++it) {
      int f = it * 256 + tid;
      int r = f >> 3, c4 = f & 7;
      float4 v = *(const float4*)(A + (size_t)(it0 + r) * 256 + k0 + c4 * 4);
      Ast[c4 * 4 + 0][r] = v.x;
      Ast[c4 * 4 + 1][r] = v.y;
      Ast[c4 * 4 + 2][r] = v.z;
      Ast[c4 * 4 + 3][r] = v.w;
    }
#pragma unroll
    for (int it = 0; it < 4; ++it) {
      int kr = (tid >> 5) + it * 8;
      int c4 = tid & 31;
      *(float4*)&Bs[kr][c4 * 4] =
          *(const float4*)(Bm + (size_t)(k0 + kr) * 512 + dt0 + c4 * 4);
    }
    __syncthreads();
#pragma unroll 8
    for (int k = 0; k < 32; ++k) {
      float4 av = *(const float4*)&Ast[k][ty * 4];
      float4 b0 = *(const float4*)&Bs[k][tx * 4];
      float4 b1 = *(const float4*)&Bs[k][64 + tx * 4];
      float avv[4] = {av.x, av.y, av.z, av.w};
      float bv[8] = {b0.x, b0.y, b0.z, b0.w, b1.x, b1.y, b1.z, b1.w};
#pragma unroll
      for (int i = 0; i < 4; ++i)
#pragma unroll
        for (int j = 0; j < 8; ++j)
          acc[i][j] = fmaf(avv[i], bv[j], acc[i][j]);
    }
    __syncthreads();
  }
#pragma unroll
  for (int ii = 0; ii < 4; ++ii) {
    int i = it0 + ty * 4 + ii;
    float* arow = accum + (size_t)bl * 131072 + (size_t)i * 512 + dt0;
#pragma unroll
    for (int j = 0; j < 4; ++j) arow[tx * 4 + j] += acc[ii][j];
#pragma unroll
    for (int j = 0; j < 4; ++j) arow[64 + tx * 4 + j] += acc[ii][4 + j];
  }
}

// ---------------------------------------------------------------------------
// FF2: 64(token) x 128(outd) block, 640 blocks, single-buf LDS 24KB.
// r2-proven: launch_bounds(256,4) + product-pass reorder with j-pairs.
//  emode 0 (bu):      accum = lv + v            (store, levels 1..5)
//  emode 1 (td):      l==0: accum=lv+tokens+v;  else accum += v
// (r4's K-split + atomicAdd additive-accum regressed ~256us — reverted.)
// ---------------------------------------------------------------------------
__global__ __launch_bounds__(256, 4) void mfma_ff2(
    const short* __restrict__ hpk, const short* __restrict__ Wb,
    const float* __restrict__ b2, const float* __restrict__ lv,
    const float* __restrict__ tokens, float* __restrict__ accum,
    int olvbase, int emode)
{
  const int per_x = gridDim.x >> 3;
  const int gid = (blockIdx.x & 7) * per_x + (blockIdx.x >> 3);
  const int nt2 = gid & 3;
  const int tile = gid >> 2;
  const int mt2 = tile & 31;          // 64-token tiles
  const int z = tile >> 5;

  __shared__ __align__(16) short SA[4096];   // hi 2048 | lo 2048
  __shared__ __align__(16) short SB[8192];   // hi 4096 | lo 4096
  const int tid = threadIdx.x, lane = tid & 63, w = tid >> 6;
  const int wm = (w >> 1) * 32, wn = (w & 1) * 64;
  const short* gaBase = hpk + (size_t)(z * 16 + (mt2 >> 1)) * 64 * 8192
                        + (size_t)(mt2 & 1) * 2048;
  const short* gb = Wb + (size_t)(z * 4 + nt2) * 64 * 8192;

  f32x4 acc[2][4];
#pragma unroll
  for (int i = 0; i < 2; ++i)
#pragma unroll
    for (int j = 0; j < 4; ++j) acc[i][j] = (f32x4)(0.0f);

  for (int kt = 0; kt < 64; ++kt) {
    __syncthreads();
    const char* pa = (const char*)(gaBase + (size_t)kt * 8192);
    const char* pb = (const char*)(gb + (size_t)kt * 8192);
    gload16(pa + w * 1024 + lane * 16, (char*)SA + w * 1024);
    gload16(pa + 8192 + w * 1024 + lane * 16, (char*)SA + 4096 + w * 1024);
#pragma unroll
    for (int c = 0; c < 4; ++c)
      gload16(pb + w * 4096 + c * 1024 + lane * 16,
              (char*)SB + w * 4096 + c * 1024);
    __syncthreads();
    bf16x8 ah[2], al[2];
#pragma unroll
    for (int i = 0; i < 2; ++i) {
      int f = (wm >> 4) + i;
      ah[i] = *(const bf16x8*)&SA[f * 512 + lane * 8];
      al[i] = *(const bf16x8*)&SA[2048 + f * 512 + lane * 8];
    }
#pragma unroll
    for (int jp = 0; jp < 2; ++jp) {
      bf16x8 bh[2], bl[2];
#pragma unroll
      for (int j2 = 0; j2 < 2; ++j2) {
        int f = (wn >> 4) + jp * 2 + j2;
        bh[j2] = *(const bf16x8*)&SB[f * 512 + lane * 8];
        bl[j2] = *(const bf16x8*)&SB[4096 + f * 512 + lane * 8];
      }
#pragma unroll
      for (int j2 = 0; j2 < 2; ++j2)
#pragma unroll
        for (int i = 0; i < 2; ++i)
          acc[i][jp * 2 + j2] = __builtin_amdgcn_mfma_f32_16x16x32_bf16(
              ah[i], bh[j2], acc[i][jp * 2 + j2], 0, 0, 0);
#pragma unroll
      for (int j2 = 0; j2 < 2; ++j2)
#pragma unroll
        for (int i = 0; i < 2; ++i)
          acc[i][jp * 2 + j2] = __builtin_amdgcn_mfma_f32_16x16x32_bf16(
              al[i], bh[j2], acc[i][jp * 2 + j2], 0, 0, 0);
#pragma unroll
      for (int j2 = 0; j2 < 2; ++j2)
#pragma unroll
        for (int i = 0; i < 2; ++i)
          acc[i][jp * 2 + j2] = __builtin_amdgcn_mfma_f32_16x16x32_bf16(
              ah[i], bl[j2], acc[i][jp * 2 + j2], 0, 0, 0);
    }
  }

  const int q = lane >> 4, t = lane & 15;
  const float* b2g = b2 + (size_t)z * 512;
  const int level = olvbase + z;
#pragma unroll
  for (int i = 0; i < 2; ++i) {
#pragma unroll
    for (int r = 0; r < 4; ++r) {
      int m = mt2 * 64 + wm + i * 16 + q * 4 + r;
      int b = m >> 8, n = m & 255;
      size_t rowoff = ((size_t)(b * L6 + level) * 256 + n) * 512;
      float* arow = accum + rowoff;
      const float* lrow = lv + rowoff;
      const float* trow = tokens + (size_t)m * 512;
#pragma unroll
      for (int j = 0; j < 4; ++j) {
        int col = nt2 * 128 + wn + j * 16 + t;
        float v = acc[i][j][r] + b2g[col];
        if (emode == 0)                       arow[col] = lrow[col] + v;
        else if (level == 0)                  arow[col] = lrow[col] + trow[col] + v;
        else                                  arow[col] += v;
      }
    }
  }
}

// ---------------------------------------------------------------------------
// combine3: lv = accum/contrib, write dout on last iter, fused next-iter
// A-packing. Grid 3072.
// ---------------------------------------------------------------------------
__global__ __launch_bounds__(256) void combine3(
    const float* __restrict__ accum, const float* __restrict__ pos,
    float* __restrict__ lv_out, short* __restrict__ Abu,
    short* __restrict__ Atd, float* __restrict__ dout, int last)
{
  int t = blockIdx.x * 256 + threadIdx.x;   // 786,432 total
  int d8 = t & 63;
  int n = (t >> 6) & 255;
  int v = t >> 14;                          // b*6 + l, 0..47
  int l = v % 6, b = v / 6;
  int bn = (b << 8) | n;
  size_t idx = ((size_t)v * 256 + n) * 512 + d8 * 8;
  float4 a0 = *(const float4*)(accum + idx);
  float4 a1 = *(const float4*)(accum + idx + 4);
  float sc = (l == 5) ? (1.0f / 3.0f) : 0.25f;
  float r[8];
  r[0] = a0.x * sc; r[1] = a0.y * sc; r[2] = a0.z * sc; r[3] = a0.w * sc;
  r[4] = a1.x * sc; r[5] = a1.y * sc; r[6] = a1.z * sc; r[7] = a1.w * sc;
  *(float4*)(lv_out + idx) = make_float4(r[0], r[1], r[2], r[3]);
  *(float4*)(lv_out + idx + 4) = make_float4(r[4], r[5], r[6], r[7]);
  if (last) {
    float* dp = dout + ((size_t)bn * 6 + l) * 512 + d8 * 8;
    *(float4*)dp = make_float4(r[0], r[1], r[2], r[3]);
    *(float4*)(dp + 4) = make_float4(r[4], r[5], r[6], r[7]);
  }
  int m = bn;
  int mt = m >> 7;
  int kt = d8 >> 2;
  int s = (((m & 127) >> 4) << 6) | (((d8 & 3) << 4) | (m & 15));
  unsigned short hi[8], lo[8];
  if (l < 5) {
    size_t blk = ((size_t)(l * 16 + mt) * 16 + kt) * 8192;
#pragma unroll
    for (int j = 0; j < 8; ++j) split2(r[j], &hi[j], &lo[j]);
    *(int4*)(Abu + blk + s * 8) = pack8(hi);
    *(int4*)(Abu + blk + 4096 + s * 8) = pack8(lo);
  }
  if (l >= 1) {
    const float* pp = pos + (size_t)n * 512 + d8 * 8;
    float4 p0 = *(const float4*)pp;
    float4 p1 = *(const float4*)(pp + 4);
    float y[8] = {r[0] + p0.x, r[1] + p0.y, r[2] + p0.z, r[3] + p0.w,
                  r[4] + p1.x, r[5] + p1.y, r[6] + p1.z, r[7] + p1.w};
    size_t blk = ((size_t)((l - 1) * 16 + mt) * 16 + kt) * 8192;
#pragma unroll
    for (int j = 0; j < 8; ++j) split2(y[j], &hi[j], &lo[j]);
    *(int4*)(Atd + blk + s * 8) = pack8(hi);
    *(int4*)(Atd + blk + 4096 + s * 8) = pack8(lo);
  }
}

// ---------------------------------------------------------------------------
extern "C" void kernel_launch(void* const* d_in, const int* in_sizes, int n_in,
                              void* d_out, int out_size, void* d_ws, size_t ws_size,
                              hipStream_t stream)
{
  const float* img   = (const float*)d_in[0];
  const float* Wp    = (const float*)d_in[1];
  const float* bp    = (const float*)d_in[2];
  const float* pos   = (const float*)d_in[3];
  const float* initl = (const float*)d_in[4];
  const float* buW1  = (const float*)d_in[5];
  const float* bub1  = (const float*)d_in[6];
  const float* buW2  = (const float*)d_in[7];
  const float* bub2  = (const float*)d_in[8];
  const float* tdW1  = (const float*)d_in[9];
  const float* tdb1  = (const float*)d_in[10];
  const float* tdW2  = (const float*)d_in[11];
  const float* tdb2  = (const float*)d_in[12];

  float* ws = (float*)d_ws;
  const size_t LV = (size_t)8 * 6 * 256 * 512;   // 6,291,456 floats
  float* lv     = ws;
  float* tokens = lv + LV;                        // 1,048,576
  float* accum  = tokens + 1048576ull;            // 6,291,456
  short* W1all  = (short*)(accum + LV);           // 20,971,520 shorts
  short* W2all  = W1all + 20971520ull;            // 20,971,520 shorts
  short* Apk    = W2all + 20971520ull;            // 20,971,520 shorts
  short* hall   = Apk + 20971520ull;              // 41,943,040 shorts (5z hi/lo)
  // total = 264,241,152 B <= 264,290,304 B proven to fit (round 3)

  // attnb aliases hall's upper half (12.6 MB needed, 42 MB available);
  // it lives only between attn_k and cons_k, and hall is rewritten by the
  // NEXT iteration's ff1 passes after cons_k has consumed it.
  float* attnb = (float*)(hall + 20971520ull);
  float* dout  = (float*)d_out;

  pack_w<<<2560, 256, 0, stream>>>(buW1, W1all, 16, 16);
  pack_w<<<2560, 256, 0, stream>>>(tdW1, W1all + 5 * SH_W_GRP, 16, 16);
  pack_w<<<2560, 256, 0, stream>>>(buW2, W2all, 64, 4);
  pack_w<<<2560, 256, 0, stream>>>(tdW2, W2all + 5 * SH_W_GRP, 64, 4);

  patch_embed<<<2048, 256, 0, stream>>>(img, Wp, bp, tokens);
  init_lv_kernel<<<6144, 256, 0, stream>>>(initl, lv);
  pack_A<<<1280, 256, 0, stream>>>(lv, pos, Apk, Apk + SH_A_TDOFF);

  for (int it = 0; it < 12; ++it) {
    // K1: ff1-bu (fills hall)
    ff1_k<<<1280, 256, 0, stream>>>(W1all, Apk, bub1, hall);
    // K2: ff2-bu emode0 (store accum = lv + v, levels 1..5)
    mfma_ff2<<<640, 256, 0, stream>>>(hall, W2all, bub2, lv, tokens, accum, 1, 0);
    // K3: ff1-td (refills hall)
    ff1_k<<<1280, 256, 0, stream>>>(W1all + 5 * SH_W_GRP, Apk + SH_A_TDOFF,
                                    tdb1, hall);
    // K4: ff2-td emode1 (level0 store lv+tokens+v; levels 1..4 RMW)
    mfma_ff2<<<640, 256, 0, stream>>>(hall, W2all + 5 * SH_W_GRP, tdb2, lv,
                                      tokens, accum, 0, 1);
    // K5: attention (writes attnb over hall's upper half — hall is dead)
    attn_k<<<768, 256, 0, stream>>>(lv, attnb);
    // K6: consensus RMW into accum
    cons_k<<<768, 256, 0, stream>>>(attnb, lv, accum);
    // K7: combine + dout + next-iter A-pack
    combine3<<<3072, 256, 0, stream>>>(accum, pos, lv, Apk, Apk + SH_A_TDOFF,
                                       dout, it == 11 ? 1 : 0);
  }
}

// Round 6
// 5073.362 us; speedup vs baseline: 1.0779x; 1.0724x over previous
//
#include <hip/hip_runtime.h>
#include <math.h>

// Problem constants: B=8, S=224, P=14, D=512, L=6, NPS=16, N=256, G=5, H=2048, iters=12
#define L6 6

typedef __attribute__((ext_vector_type(8))) short bf16x8;   // 8 bf16 in 4 VGPRs
typedef __attribute__((ext_vector_type(4))) float f32x4;    // MFMA accum

#define SH_W_GRP   2097152ull   // 512*2048 hi/lo bf16 (both W1 and W2)
#define SH_A_GRP   2097152ull   // 2048 tok * 512 d hi/lo
#define SH_A_TDOFF 10485760ull  // Atd offset inside Apk (5 groups)

// Exact gelu (erff): r10-proven epilogue.
__device__ __forceinline__ float gelu_exact(float x) {
  return 0.5f * x * (1.0f + erff(x * 0.70710678118654752f));
}

__device__ __forceinline__ unsigned short bf16_rn(float x) {
  unsigned u = __float_as_uint(x);
  unsigned r = u + 0x7FFFu + ((u >> 16) & 1u);
  return (unsigned short)(r >> 16);
}
__device__ __forceinline__ float bf16_f(unsigned short h) {
  return __uint_as_float(((unsigned)h) << 16);
}
__device__ __forceinline__ void split2(float x, unsigned short* h, unsigned short* l) {
  unsigned short hh = bf16_rn(x);
  *h = hh;
  *l = bf16_rn(x - bf16_f(hh));
}
__device__ __forceinline__ int4 pack8(const unsigned short* v) {
  return make_int4((int)((unsigned)v[0] | ((unsigned)v[1] << 16)),
                   (int)((unsigned)v[2] | ((unsigned)v[3] << 16)),
                   (int)((unsigned)v[4] | ((unsigned)v[5] << 16)),
                   (int)((unsigned)v[6] | ((unsigned)v[7] << 16)));
}

__device__ __forceinline__ void gload16(const void* g, void* l) {
  __builtin_amdgcn_global_load_lds(
      (const __attribute__((address_space(1))) void*)g,
      (__attribute__((address_space(3))) void*)l, 16, 0, 0);
}

// ---------------------------------------------------------------------------
// Patch embedding
// ---------------------------------------------------------------------------
__global__ __launch_bounds__(256) void patch_embed(
    const float* __restrict__ img, const float* __restrict__ Wp,
    const float* __restrict__ bp, float* __restrict__ tokens)
{
  __shared__ float xs[588];
  const int bn = blockIdx.x;
  const int b = bn >> 8, n = bn & 255;
  const int i = n >> 4, j = n & 15;
  for (int k = threadIdx.x; k < 588; k += 256) {
    int c = k % 3;
    int t = k / 3;
    int pc = t % 14;
    int pr = t / 14;
    xs[k] = img[(((size_t)(b * 3 + c) * 224) + (i * 14 + pr)) * 224 + (j * 14 + pc)];
  }
  __syncthreads();
  const int d0 = threadIdx.x, d1 = threadIdx.x + 256;
  float a0 = 0.f, a1 = 0.f;
  for (int k = 0; k < 588; ++k) {
    float x = xs[k];
    a0 = fmaf(x, Wp[(size_t)k * 512 + d0], a0);
    a1 = fmaf(x, Wp[(size_t)k * 512 + d1], a1);
  }
  tokens[(size_t)bn * 512 + d0] = a0 + bp[d0];
  tokens[(size_t)bn * 512 + d1] = a1 + bp[d1];
}

// ---------------------------------------------------------------------------
__global__ __launch_bounds__(256) void init_lv_kernel(
    const float* __restrict__ initl, float* __restrict__ lv)
{
  int f = blockIdx.x * 256 + threadIdx.x;
  int d4 = f & 127;
  int l = (f >> 15) % 6;
  float4 v = *(const float4*)(initl + (size_t)l * 512 + d4 * 4);
  *(float4*)(lv + (size_t)f * 4) = v;
}

// ---------------------------------------------------------------------------
// Pack weights fp32 [G][K][N] -> hi/lo bf16 fragment-image.
// ---------------------------------------------------------------------------
__global__ __launch_bounds__(256) void pack_w(
    const float* __restrict__ src, short* __restrict__ dst, int KT, int NT)
{
  int sidx = blockIdx.x * 256 + threadIdx.x;
  int slot = sidx & 511;
  int blk = sidx >> 9;
  int kt = blk % KT;
  int rest = blk / KT;
  int nt = rest % NT;
  int g = rest / NT;
  int f = slot >> 6, lane = slot & 63;
  int N = NT * 128, K = KT * 32;
  int n = nt * 128 + f * 16 + (lane & 15);
  int k0 = kt * 32 + (lane >> 4) * 8;
  const float* s = src + ((size_t)g * K + k0) * N + n;
  unsigned short hi[8], lo[8];
#pragma unroll
  for (int j = 0; j < 8; ++j) split2(s[(size_t)j * N], &hi[j], &lo[j]);
  short* d = dst + (size_t)blk * 8192 + slot * 8;
  *(int4*)d = pack8(hi);
  *(int4*)(d + 4096) = pack8(lo);
}

// ---------------------------------------------------------------------------
// Startup A-pack (steady-state fused into combine3).
// ---------------------------------------------------------------------------
__global__ __launch_bounds__(256) void pack_A(
    const float* __restrict__ lv, const float* __restrict__ pos,
    short* __restrict__ Abu, short* __restrict__ Atd)
{
  const int bx = blockIdx.x;              // 0..1279
  const int lg = bx >> 8, mt = (bx >> 4) & 15, kt = bx & 15;
  const size_t blk = (size_t)bx * 8192;
#pragma unroll
  for (int ss = 0; ss < 2; ++ss) {
    int s = threadIdx.x + ss * 256;
    int f = s >> 6, l = s & 63;
    int m = mt * 128 + (f << 4) + (l & 15);
    int b = m >> 8, n = m & 255;
    int d = kt * 32 + ((l >> 4) << 3);
    const float* pbu = lv + ((size_t)(b * L6 + lg) * 256 + n) * 512 + d;
    const float* ptd = lv + ((size_t)(b * L6 + lg + 1) * 256 + n) * 512 + d;
    const float* pp = pos + (size_t)n * 512 + d;
    float4 u0 = *(const float4*)pbu;
    float4 u1 = *(const float4*)(pbu + 4);
    float xv[8] = {u0.x, u0.y, u0.z, u0.w, u1.x, u1.y, u1.z, u1.w};
    unsigned short hi[8], lo[8];
#pragma unroll
    for (int j = 0; j < 8; ++j) split2(xv[j], &hi[j], &lo[j]);
    *(int4*)(Abu + blk + s * 8) = pack8(hi);
    *(int4*)(Abu + blk + 4096 + s * 8) = pack8(lo);
    float4 v0 = *(const float4*)ptd;
    float4 v1 = *(const float4*)(ptd + 4);
    float4 p0 = *(const float4*)pp;
    float4 p1 = *(const float4*)(pp + 4);
    float yv[8] = {v0.x + p0.x, v0.y + p0.y, v0.z + p0.z, v0.w + p0.w,
                   v1.x + p1.x, v1.y + p1.y, v1.z + p1.z, v1.w + p1.w};
#pragma unroll
    for (int j = 0; j < 8; ++j) split2(yv[j], &hi[j], &lo[j]);
    *(int4*)(Atd + blk + s * 8) = pack8(hi);
    *(int4*)(Atd + blk + 4096 + s * 8) = pack8(lo);
  }
}

// ---------------------------------------------------------------------------
// FF1: h^T = W1^T @ lv^T, bf16x2, 128x128 block, single-buf LDS 32KB.
// r2-proven config (109us, MfmaUtil 24%, occ 33%). r1/r3 pipelining variants
// both regressed — do not re-add.
// ---------------------------------------------------------------------------
__global__ __launch_bounds__(256, 3) void ff1_k(
    const short* __restrict__ Wa, const short* __restrict__ Ap,
    const float* __restrict__ b1, short* __restrict__ hpk)
{
  __shared__ __align__(16) short SA[8192];
  __shared__ __align__(16) short SB[8192];
  const int per_x = gridDim.x >> 3;
  const int gid = (blockIdx.x & 7) * per_x + (blockIdx.x >> 3);
  const int tt = gid & 15;
  const int tile = gid >> 4;
  const int ht = tile & 15;
  const int z = tile >> 4;
  const int tid = threadIdx.x, lane = tid & 63, w = tid >> 6;
  const int wm = (w >> 1) * 64, wn = (w & 1) * 64;
  const short* ga = Wa + (size_t)(z * 16 + ht) * 16 * 8192;
  const short* gb = Ap + (size_t)(z * 16 + tt) * 16 * 8192;
  const int soff = w * 4096 + lane * 16;

  f32x4 acc[4][4];
#pragma unroll
  for (int i = 0; i < 4; ++i)
#pragma unroll
    for (int j = 0; j < 4; ++j) acc[i][j] = (f32x4)(0.0f);

  for (int kt = 0; kt < 16; ++kt) {
    __syncthreads();
    const char* pa = (const char*)(ga + (size_t)kt * 8192);
    const char* pb = (const char*)(gb + (size_t)kt * 8192);
#pragma unroll
    for (int c = 0; c < 4; ++c) {
      gload16(pa + soff + c * 1024, (char*)SA + w * 4096 + c * 1024);
      gload16(pb + soff + c * 1024, (char*)SB + w * 4096 + c * 1024);
    }
    __syncthreads();
    bf16x8 ah[4], al[4];
#pragma unroll
    for (int i = 0; i < 4; ++i) {
      int f = (wm >> 4) + i;
      ah[i] = *(const bf16x8*)&SA[f * 512 + lane * 8];
      al[i] = *(const bf16x8*)&SA[4096 + f * 512 + lane * 8];
    }
#pragma unroll
    for (int jp = 0; jp < 2; ++jp) {
      bf16x8 bh[2], bl[2];
#pragma unroll
      for (int j2 = 0; j2 < 2; ++j2) {
        int f = (wn >> 4) + jp * 2 + j2;
        bh[j2] = *(const bf16x8*)&SB[f * 512 + lane * 8];
        bl[j2] = *(const bf16x8*)&SB[4096 + f * 512 + lane * 8];
      }
      // pass 1: A_hi * B_hi (8 independent MFMAs)
#pragma unroll
      for (int j2 = 0; j2 < 2; ++j2)
#pragma unroll
        for (int i = 0; i < 4; ++i)
          acc[i][jp * 2 + j2] = __builtin_amdgcn_mfma_f32_16x16x32_bf16(
              ah[i], bh[j2], acc[i][jp * 2 + j2], 0, 0, 0);
      // pass 2: A_lo * B_hi
#pragma unroll
      for (int j2 = 0; j2 < 2; ++j2)
#pragma unroll
        for (int i = 0; i < 4; ++i)
          acc[i][jp * 2 + j2] = __builtin_amdgcn_mfma_f32_16x16x32_bf16(
              al[i], bh[j2], acc[i][jp * 2 + j2], 0, 0, 0);
      // pass 3: A_hi * B_lo
#pragma unroll
      for (int j2 = 0; j2 < 2; ++j2)
#pragma unroll
        for (int i = 0; i < 4; ++i)
          acc[i][jp * 2 + j2] = __builtin_amdgcn_mfma_f32_16x16x32_bf16(
              ah[i], bl[j2], acc[i][jp * 2 + j2], 0, 0, 0);
    }
  }

  const int q = lane >> 4, t = lane & 15;
  const float* b1g = b1 + (size_t)z * 2048;
#pragma unroll
  for (int i = 0; i < 4; ++i) {
    int Hb = ht * 128 + wm + i * 16 + q * 4;
    float4 bv = *(const float4*)(b1g + Hb);
    float bb[4] = {bv.x, bv.y, bv.z, bv.w};
    int kt2 = Hb >> 5;
    int g2 = (Hb >> 3) & 3;
    int jb = Hb & 7;                       // 0 or 4
    size_t blkbase = ((size_t)(z * 16 + tt) * 64 + kt2) * 8192;
#pragma unroll
    for (int j = 0; j < 4; ++j) {
      int f2 = (wn >> 4) + j;
      size_t off = blkbase + (size_t)(f2 * 64 + g2 * 16 + t) * 8 + jb;
      unsigned short hi[4], lo[4];
#pragma unroll
      for (int r = 0; r < 4; ++r) {
        float x = gelu_exact(acc[i][j][r] + bb[r]);
        split2(x, &hi[r], &lo[r]);
      }
      *(uint2*)(hpk + off) =
          make_uint2((unsigned)hi[0] | ((unsigned)hi[1] << 16),
                     (unsigned)hi[2] | ((unsigned)hi[3] << 16));
      *(uint2*)(hpk + off + 4096) =
          make_uint2((unsigned)lo[0] | ((unsigned)lo[1] << 16),
                     (unsigned)lo[2] | ((unsigned)lo[3] << 16));
    }
  }
}

// ---------------------------------------------------------------------------
// Attention r6: MFMA Gram. sim = (lv·lv^T)·invn[j]·rs. B-panel (256 tok x
// 32 k hi/lo) gload16'd DIRECTLY from Apk's bu-image (levels 0..4 = packed
// CURRENT lv; intact until combine3 at K7). A-fragments are a row-subset of
// the same panel -> zero A staging. Level 5 (no clean image, Atd is
// pos-polluted) packs on the fly via split2 from the fp32 reads. Norms stay
// fp32-exact with the r2 summation order (same bits). Gram via proven
// hh/lh/hl bf16x2 3-pass. Block = 32 i x 256 j, grid 48 bl x 8 = 384.
// Cross-wave softmax via 32x4 LDS reduce.
// ---------------------------------------------------------------------------
__global__ __launch_bounds__(256, 3) void attn_k(
    const float* __restrict__ lv, const short* __restrict__ Apk,
    float* __restrict__ attnb)
{
  __shared__ __align__(16) short Bhi[8192];   // 16 frags x 64 lanes x 8
  __shared__ __align__(16) short Blo[8192];
  __shared__ float scL[256];
  __shared__ float red[32][4];
  const int a = blockIdx.x;
  const int s = a >> 3;
  const int b = a & 7;                 // batch == XCD group
  const int l = s >> 3;                // level 0..5
  const int bl = b * 6 + l;
  const int i0 = (s & 7) * 32;
  const float* base = lv + (size_t)bl * 131072;
  const int tid = threadIdx.x, lane = tid & 63, w = tid >> 6;
  const int q = lane >> 4, c = lane & 15;

  f32x4 acc[2][4];
#pragma unroll
  for (int i = 0; i < 2; ++i)
#pragma unroll
    for (int j = 0; j < 4; ++j) acc[i][j] = (f32x4)(0.0f);
  float ss[8] = {0.f, 0.f, 0.f, 0.f, 0.f, 0.f, 0.f, 0.f};

  // Apk bu-image sub-blocks for this (b,l): tokens n 0..127 -> tile 2b,
  // n 128..255 -> tile 2b+1. Valid only for l<5.
  const short* src0 = Apk + ((size_t)(l * 16 + 2 * b) * 16) * 8192;
  const short* src1 = Apk + ((size_t)(l * 16 + 2 * b + 1) * 16) * 8192;

  for (int kt = 0; kt < 16; ++kt) {
    const int k0 = kt * 32;
    __syncthreads();                    // prev step's LDS reads done
    if (l < 5) {
      const char* p0 = (const char*)(src0 + (size_t)kt * 8192);
      const char* p1 = (const char*)(src1 + (size_t)kt * 8192);
      gload16(p0 + tid * 16,         (char*)Bhi + tid * 16);
      gload16(p0 + 4096 + tid * 16,  (char*)Bhi + 4096 + tid * 16);
      gload16(p0 + 8192 + tid * 16,  (char*)Blo + tid * 16);
      gload16(p0 + 12288 + tid * 16, (char*)Blo + 4096 + tid * 16);
      gload16(p1 + tid * 16,         (char*)Bhi + 8192 + tid * 16);
      gload16(p1 + 4096 + tid * 16,  (char*)Bhi + 12288 + tid * 16);
      gload16(p1 + 8192 + tid * 16,  (char*)Blo + 8192 + tid * 16);
      gload16(p1 + 12288 + tid * 16, (char*)Blo + 12288 + tid * 16);
    }
    // fp32 reads for exact norms (identical order to r2 version); for l==5
    // these also feed the on-the-fly hi/lo pack.
#pragma unroll
    for (int it = 0; it < 8; ++it) {
      int f = it * 256 + tid;
      int j = f >> 3, c4 = f & 7;
      float4 v = *(const float4*)(base + (size_t)j * 512 + k0 + c4 * 4);
      ss[it] += v.x * v.x + v.y * v.y + v.z * v.z + v.w * v.w;
      if (l == 5) {
        unsigned short hi[4], lo[4];
        split2(v.x, &hi[0], &lo[0]);
        split2(v.y, &hi[1], &lo[1]);
        split2(v.z, &hi[2], &lo[2]);
        split2(v.w, &hi[3], &lo[3]);
        int fg = j >> 4;
        int la = (c4 >> 1) * 16 + (j & 15);
        int half = (c4 & 1) * 4;
        *(uint2*)&Bhi[fg * 512 + la * 8 + half] =
            make_uint2((unsigned)hi[0] | ((unsigned)hi[1] << 16),
                       (unsigned)hi[2] | ((unsigned)hi[3] << 16));
        *(uint2*)&Blo[fg * 512 + la * 8 + half] =
            make_uint2((unsigned)lo[0] | ((unsigned)lo[1] << 16),
                       (unsigned)lo[2] | ((unsigned)lo[3] << 16));
      }
    }
    __syncthreads();                    // staging complete
    bf16x8 ah[2], al[2], bh[4], blv[4];
#pragma unroll
    for (int i = 0; i < 2; ++i) {
      int fg = (i0 >> 4) + i;
      ah[i] = *(const bf16x8*)&Bhi[fg * 512 + lane * 8];
      al[i] = *(const bf16x8*)&Blo[fg * 512 + lane * 8];
    }
#pragma unroll
    for (int j = 0; j < 4; ++j) {
      int fg = w * 4 + j;
      bh[j] = *(const bf16x8*)&Bhi[fg * 512 + lane * 8];
      blv[j] = *(const bf16x8*)&Blo[fg * 512 + lane * 8];
    }
#pragma unroll
    for (int j = 0; j < 4; ++j)
#pragma unroll
      for (int i = 0; i < 2; ++i)
        acc[i][j] = __builtin_amdgcn_mfma_f32_16x16x32_bf16(
            ah[i], bh[j], acc[i][j], 0, 0, 0);
#pragma unroll
    for (int j = 0; j < 4; ++j)
#pragma unroll
      for (int i = 0; i < 2; ++i)
        acc[i][j] = __builtin_amdgcn_mfma_f32_16x16x32_bf16(
            al[i], bh[j], acc[i][j], 0, 0, 0);
#pragma unroll
    for (int j = 0; j < 4; ++j)
#pragma unroll
      for (int i = 0; i < 2; ++i)
        acc[i][j] = __builtin_amdgcn_mfma_f32_16x16x32_bf16(
            ah[i], blv[j], acc[i][j], 0, 0, 0);
  }

  // norms (same reduce as r2): scL[j] = 1/max(||lv[j]||,1e-12)
#pragma unroll
  for (int it = 0; it < 8; ++it) {
    float sv = ss[it];
    sv += __shfl_xor(sv, 1);
    sv += __shfl_xor(sv, 2);
    sv += __shfl_xor(sv, 4);
    if ((tid & 7) == 0) scL[(it * 256 + tid) >> 3] = 1.0f / fmaxf(sqrtf(sv), 1e-12f);
  }
  __syncthreads();

  const float rs = 0.04419417382415922f;  // 512^-0.5
  // scale + diag; value at (ai,bj,r): i = i0+ai*16+q*4+r, j = w*64+bj*16+c
#pragma unroll
  for (int ai = 0; ai < 2; ++ai)
#pragma unroll
    for (int bj = 0; bj < 4; ++bj)
#pragma unroll
      for (int r = 0; r < 4; ++r) {
        int i = i0 + ai * 16 + q * 4 + r;
        int j = w * 64 + bj * 16 + c;
        float sv = acc[ai][bj][r] * scL[j] * rs;
        if (j == i) sv = -0.0005f;
        acc[ai][bj][r] = sv;
      }
  // wave-local row max (over this wave's 64 j), then cross-wave via red
  float mx[2][4];
#pragma unroll
  for (int ai = 0; ai < 2; ++ai)
#pragma unroll
    for (int r = 0; r < 4; ++r) {
      float m = fmaxf(fmaxf(acc[ai][0][r], acc[ai][1][r]),
                      fmaxf(acc[ai][2][r], acc[ai][3][r]));
      m = fmaxf(m, __shfl_xor(m, 1));
      m = fmaxf(m, __shfl_xor(m, 2));
      m = fmaxf(m, __shfl_xor(m, 4));
      m = fmaxf(m, __shfl_xor(m, 8));
      mx[ai][r] = m;
    }
  if (c == 0) {
#pragma unroll
    for (int ai = 0; ai < 2; ++ai)
#pragma unroll
      for (int r = 0; r < 4; ++r) red[ai * 16 + q * 4 + r][w] = mx[ai][r];
  }
  __syncthreads();
#pragma unroll
  for (int ai = 0; ai < 2; ++ai)
#pragma unroll
    for (int r = 0; r < 4; ++r) {
      int row = ai * 16 + q * 4 + r;
      mx[ai][r] = fmaxf(fmaxf(red[row][0], red[row][1]),
                        fmaxf(red[row][2], red[row][3]));
    }
  __syncthreads();                      // before red reuse for sums
  float sm[2][4];
#pragma unroll
  for (int ai = 0; ai < 2; ++ai)
#pragma unroll
    for (int r = 0; r < 4; ++r) {
      float t = 0.f;
#pragma unroll
      for (int bj = 0; bj < 4; ++bj) {
        float e = expf(acc[ai][bj][r] - mx[ai][r]);
        acc[ai][bj][r] = e;
        t += e;
      }
      t += __shfl_xor(t, 1);
      t += __shfl_xor(t, 2);
      t += __shfl_xor(t, 4);
      t += __shfl_xor(t, 8);
      sm[ai][r] = t;
    }
  if (c == 0) {
#pragma unroll
    for (int ai = 0; ai < 2; ++ai)
#pragma unroll
      for (int r = 0; r < 4; ++r) red[ai * 16 + q * 4 + r][w] = sm[ai][r];
  }
  __syncthreads();
  float* ob = attnb + (size_t)bl * 65536;
#pragma unroll
  for (int ai = 0; ai < 2; ++ai)
#pragma unroll
    for (int r = 0; r < 4; ++r) {
      int row = ai * 16 + q * 4 + r;
      float S = red[row][0] + red[row][1] + red[row][2] + red[row][3];
      float inv = 1.0f / S;
      int i = i0 + row;
#pragma unroll
      for (int bj = 0; bj < 4; ++bj) {
        int j = w * 64 + bj * 16 + c;
        ob[(size_t)i * 256 + j] = acc[ai][bj][r] * inv;
      }
    }
}

// ---------------------------------------------------------------------------
// Consensus: accum += attnb @ lv (pure RMW). Grid 768, XCD-grouped by bl.
// ---------------------------------------------------------------------------
__global__ __launch_bounds__(256) void cons_k(
    const float* __restrict__ attnb, const float* __restrict__ lv,
    float* __restrict__ accum)
{
  __shared__ __align__(16) char smemraw[25088];
  const int a = blockIdx.x;
  const int s = a >> 3;
  const int bl = (a & 7) * 6 + (s >> 4);
  const int tile = s & 15;
  int it0 = (tile >> 2) * 64;
  int dt0 = (tile & 3) * 128;
  const float* A = attnb + (size_t)bl * 65536;
  const float* Bm = lv + (size_t)bl * 131072;
  float (*Ast)[68] = (float(*)[68])smemraw;
  float (*Bs)[128] = (float(*)[128])(smemraw + 8704);
  const int tid = threadIdx.x;
  const int ty = tid >> 4, tx = tid & 15;
  float acc[4][8];
#pragma unroll
  for (int i = 0; i < 4; ++i)
#pragma unroll
    for (int j = 0; j < 8; ++j) acc[i][j] = 0.f;

  for (int k0 = 0; k0 < 256; k0 += 32) {
#pragma unroll
    for (int it = 0; it < 2; ++it) {
      int f = it * 256 + tid;
      int r = f >> 3, c4 = f & 7;
      float4 v = *(const float4*)(A + (size_t)(it0 + r) * 256 + k0 + c4 * 4);
      Ast[c4 * 4 + 0][r] = v.x;
      Ast[c4 * 4 + 1][r] = v.y;
      Ast[c4 * 4 + 2][r] = v.z;
      Ast[c4 * 4 + 3][r] = v.w;
    }
#pragma unroll
    for (int it = 0; it < 4; ++it) {
      int kr = (tid >> 5) + it * 8;
      int c4 = tid & 31;
      *(float4*)&Bs[kr][c4 * 4] =
          *(const float4*)(Bm + (size_t)(k0 + kr) * 512 + dt0 + c4 * 4);
    }
    __syncthreads();
#pragma unroll 8
    for (int k = 0; k < 32; ++k) {
      float4 av = *(const float4*)&Ast[k][ty * 4];
      float4 b0 = *(const float4*)&Bs[k][tx * 4];
      float4 b1 = *(const float4*)&Bs[k][64 + tx * 4];
      float avv[4] = {av.x, av.y, av.z, av.w};
      float bv[8] = {b0.x, b0.y, b0.z, b0.w, b1.x, b1.y, b1.z, b1.w};
#pragma unroll
      for (int i = 0; i < 4; ++i)
#pragma unroll
        for (int j = 0; j < 8; ++j)
          acc[i][j] = fmaf(avv[i], bv[j], acc[i][j]);
    }
    __syncthreads();
  }
#pragma unroll
  for (int ii = 0; ii < 4; ++ii) {
    int i = it0 + ty * 4 + ii;
    float* arow = accum + (size_t)bl * 131072 + (size_t)i * 512 + dt0;
#pragma unroll
    for (int j = 0; j < 4; ++j) arow[tx * 4 + j] += acc[ii][j];
#pragma unroll
    for (int j = 0; j < 4; ++j) arow[64 + tx * 4 + j] += acc[ii][4 + j];
  }
}

// ---------------------------------------------------------------------------
// FF2: 64(token) x 128(outd) block, 640 blocks, single-buf LDS 24KB.
// r2-proven: launch_bounds(256,4) + product-pass reorder with j-pairs.
//  emode 0 (bu):      accum = lv + v            (store, levels 1..5)
//  emode 1 (td):      l==0: accum=lv+tokens+v;  else accum += v
// ---------------------------------------------------------------------------
__global__ __launch_bounds__(256, 4) void mfma_ff2(
    const short* __restrict__ hpk, const short* __restrict__ Wb,
    const float* __restrict__ b2, const float* __restrict__ lv,
    const float* __restrict__ tokens, float* __restrict__ accum,
    int olvbase, int emode)
{
  const int per_x = gridDim.x >> 3;
  const int gid = (blockIdx.x & 7) * per_x + (blockIdx.x >> 3);
  const int nt2 = gid & 3;
  const int tile = gid >> 2;
  const int mt2 = tile & 31;          // 64-token tiles
  const int z = tile >> 5;

  __shared__ __align__(16) short SA[4096];   // hi 2048 | lo 2048
  __shared__ __align__(16) short SB[8192];   // hi 4096 | lo 4096
  const int tid = threadIdx.x, lane = tid & 63, w = tid >> 6;
  const int wm = (w >> 1) * 32, wn = (w & 1) * 64;
  const short* gaBase = hpk + (size_t)(z * 16 + (mt2 >> 1)) * 64 * 8192
                        + (size_t)(mt2 & 1) * 2048;
  const short* gb = Wb + (size_t)(z * 4 + nt2) * 64 * 8192;

  f32x4 acc[2][4];
#pragma unroll
  for (int i = 0; i < 2; ++i)
#pragma unroll
    for (int j = 0; j < 4; ++j) acc[i][j] = (f32x4)(0.0f);

  for (int kt = 0; kt < 64; ++kt) {
    __syncthreads();
    const char* pa = (const char*)(gaBase + (size_t)kt * 8192);
    const char* pb = (const char*)(gb + (size_t)kt * 8192);
    gload16(pa + w * 1024 + lane * 16, (char*)SA + w * 1024);
    gload16(pa + 8192 + w * 1024 + lane * 16, (char*)SA + 4096 + w * 1024);
#pragma unroll
    for (int c = 0; c < 4; ++c)
      gload16(pb + w * 4096 + c * 1024 + lane * 16,
              (char*)SB + w * 4096 + c * 1024);
    __syncthreads();
    bf16x8 ah[2], al[2];
#pragma unroll
    for (int i = 0; i < 2; ++i) {
      int f = (wm >> 4) + i;
      ah[i] = *(const bf16x8*)&SA[f * 512 + lane * 8];
      al[i] = *(const bf16x8*)&SA[2048 + f * 512 + lane * 8];
    }
#pragma unroll
    for (int jp = 0; jp < 2; ++jp) {
      bf16x8 bh[2], bl[2];
#pragma unroll
      for (int j2 = 0; j2 < 2; ++j2) {
        int f = (wn >> 4) + jp * 2 + j2;
        bh[j2] = *(const bf16x8*)&SB[f * 512 + lane * 8];
        bl[j2] = *(const bf16x8*)&SB[4096 + f * 512 + lane * 8];
      }
#pragma unroll
      for (int j2 = 0; j2 < 2; ++j2)
#pragma unroll
        for (int i = 0; i < 2; ++i)
          acc[i][jp * 2 + j2] = __builtin_amdgcn_mfma_f32_16x16x32_bf16(
              ah[i], bh[j2], acc[i][jp * 2 + j2], 0, 0, 0);
#pragma unroll
      for (int j2 = 0; j2 < 2; ++j2)
#pragma unroll
        for (int i = 0; i < 2; ++i)
          acc[i][jp * 2 + j2] = __builtin_amdgcn_mfma_f32_16x16x32_bf16(
              al[i], bh[j2], acc[i][jp * 2 + j2], 0, 0, 0);
#pragma unroll
      for (int j2 = 0; j2 < 2; ++j2)
#pragma unroll
        for (int i = 0; i < 2; ++i)
          acc[i][jp * 2 + j2] = __builtin_amdgcn_mfma_f32_16x16x32_bf16(
              ah[i], bl[j2], acc[i][jp * 2 + j2], 0, 0, 0);
    }
  }

  const int q = lane >> 4, t = lane & 15;
  const float* b2g = b2 + (size_t)z * 512;
  const int level = olvbase + z;
#pragma unroll
  for (int i = 0; i < 2; ++i) {
#pragma unroll
    for (int r = 0; r < 4; ++r) {
      int m = mt2 * 64 + wm + i * 16 + q * 4 + r;
      int b = m >> 8, n = m & 255;
      size_t rowoff = ((size_t)(b * L6 + level) * 256 + n) * 512;
      float* arow = accum + rowoff;
      const float* lrow = lv + rowoff;
      const float* trow = tokens + (size_t)m * 512;
#pragma unroll
      for (int j = 0; j < 4; ++j) {
        int col = nt2 * 128 + wn + j * 16 + t;
        float v = acc[i][j][r] + b2g[col];
        if (emode == 0)                       arow[col] = lrow[col] + v;
        else if (level == 0)                  arow[col] = lrow[col] + trow[col] + v;
        else                                  arow[col] += v;
      }
    }
  }
}

// ---------------------------------------------------------------------------
// combine3: lv = accum/contrib, write dout on last iter, fused next-iter
// A-packing. Grid 3072.
// ---------------------------------------------------------------------------
__global__ __launch_bounds__(256) void combine3(
    const float* __restrict__ accum, const float* __restrict__ pos,
    float* __restrict__ lv_out, short* __restrict__ Abu,
    short* __restrict__ Atd, float* __restrict__ dout, int last)
{
  int t = blockIdx.x * 256 + threadIdx.x;   // 786,432 total
  int d8 = t & 63;
  int n = (t >> 6) & 255;
  int v = t >> 14;                          // b*6 + l, 0..47
  int l = v % 6, b = v / 6;
  int bn = (b << 8) | n;
  size_t idx = ((size_t)v * 256 + n) * 512 + d8 * 8;
  float4 a0 = *(const float4*)(accum + idx);
  float4 a1 = *(const float4*)(accum + idx + 4);
  float sc = (l == 5) ? (1.0f / 3.0f) : 0.25f;
  float r[8];
  r[0] = a0.x * sc; r[1] = a0.y * sc; r[2] = a0.z * sc; r[3] = a0.w * sc;
  r[4] = a1.x * sc; r[5] = a1.y * sc; r[6] = a1.z * sc; r[7] = a1.w * sc;
  *(float4*)(lv_out + idx) = make_float4(r[0], r[1], r[2], r[3]);
  *(float4*)(lv_out + idx + 4) = make_float4(r[4], r[5], r[6], r[7]);
  if (last) {
    float* dp = dout + ((size_t)bn * 6 + l) * 512 + d8 * 8;
    *(float4*)dp = make_float4(r[0], r[1], r[2], r[3]);
    *(float4*)(dp + 4) = make_float4(r[4], r[5], r[6], r[7]);
  }
  int m = bn;
  int mt = m >> 7;
  int kt = d8 >> 2;
  int s = (((m & 127) >> 4) << 6) | (((d8 & 3) << 4) | (m & 15));
  unsigned short hi[8], lo[8];
  if (l < 5) {
    size_t blk = ((size_t)(l * 16 + mt) * 16 + kt) * 8192;
#pragma unroll
    for (int j = 0; j < 8; ++j) split2(r[j], &hi[j], &lo[j]);
    *(int4*)(Abu + blk + s * 8) = pack8(hi);
    *(int4*)(Abu + blk + 4096 + s * 8) = pack8(lo);
  }
  if (l >= 1) {
    const float* pp = pos + (size_t)n * 512 + d8 * 8;
    float4 p0 = *(const float4*)pp;
    float4 p1 = *(const float4*)(pp + 4);
    float y[8] = {r[0] + p0.x, r[1] + p0.y, r[2] + p0.z, r[3] + p0.w,
                  r[4] + p1.x, r[5] + p1.y, r[6] + p1.z, r[7] + p1.w};
    size_t blk = ((size_t)((l - 1) * 16 + mt) * 16 + kt) * 8192;
#pragma unroll
    for (int j = 0; j < 8; ++j) split2(y[j], &hi[j], &lo[j]);
    *(int4*)(Atd + blk + s * 8) = pack8(hi);
    *(int4*)(Atd + blk + 4096 + s * 8) = pack8(lo);
  }
}

// ---------------------------------------------------------------------------
extern "C" void kernel_launch(void* const* d_in, const int* in_sizes, int n_in,
                              void* d_out, int out_size, void* d_ws, size_t ws_size,
                              hipStream_t stream)
{
  const float* img   = (const float*)d_in[0];
  const float* Wp    = (const float*)d_in[1];
  const float* bp    = (const float*)d_in[2];
  const float* pos   = (const float*)d_in[3];
  const float* initl = (const float*)d_in[4];
  const float* buW1  = (const float*)d_in[5];
  const float* bub1  = (const float*)d_in[6];
  const float* buW2  = (const float*)d_in[7];
  const float* bub2  = (const float*)d_in[8];
  const float* tdW1  = (const float*)d_in[9];
  const float* tdb1  = (const float*)d_in[10];
  const float* tdW2  = (const float*)d_in[11];
  const float* tdb2  = (const float*)d_in[12];

  float* ws = (float*)d_ws;
  const size_t LV = (size_t)8 * 6 * 256 * 512;   // 6,291,456 floats
  float* lv     = ws;
  float* tokens = lv + LV;                        // 1,048,576
  float* accum  = tokens + 1048576ull;            // 6,291,456
  short* W1all  = (short*)(accum + LV);           // 20,971,520 shorts
  short* W2all  = W1all + 20971520ull;            // 20,971,520 shorts
  short* Apk    = W2all + 20971520ull;            // 20,971,520 shorts
  short* hall   = Apk + 20971520ull;              // 41,943,040 shorts (5z hi/lo)
  // total = 264,241,152 B <= 264,290,304 B proven to fit (round 3)

  // attnb aliases hall's upper half (12.6 MB needed, 42 MB available);
  // it lives only between attn_k and cons_k, and hall is rewritten by the
  // NEXT iteration's ff1 passes after cons_k has consumed it.
  float* attnb = (float*)(hall + 20971520ull);
  float* dout  = (float*)d_out;

  pack_w<<<2560, 256, 0, stream>>>(buW1, W1all, 16, 16);
  pack_w<<<2560, 256, 0, stream>>>(tdW1, W1all + 5 * SH_W_GRP, 16, 16);
  pack_w<<<2560, 256, 0, stream>>>(buW2, W2all, 64, 4);
  pack_w<<<2560, 256, 0, stream>>>(tdW2, W2all + 5 * SH_W_GRP, 64, 4);

  patch_embed<<<2048, 256, 0, stream>>>(img, Wp, bp, tokens);
  init_lv_kernel<<<6144, 256, 0, stream>>>(initl, lv);
  pack_A<<<1280, 256, 0, stream>>>(lv, pos, Apk, Apk + SH_A_TDOFF);

  for (int it = 0; it < 12; ++it) {
    // K1: ff1-bu (fills hall)
    ff1_k<<<1280, 256, 0, stream>>>(W1all, Apk, bub1, hall);
    // K2: ff2-bu emode0 (store accum = lv + v, levels 1..5)
    mfma_ff2<<<640, 256, 0, stream>>>(hall, W2all, bub2, lv, tokens, accum, 1, 0);
    // K3: ff1-td (refills hall)
    ff1_k<<<1280, 256, 0, stream>>>(W1all + 5 * SH_W_GRP, Apk + SH_A_TDOFF,
                                    tdb1, hall);
    // K4: ff2-td emode1 (level0 store lv+tokens+v; levels 1..4 RMW)
    mfma_ff2<<<640, 256, 0, stream>>>(hall, W2all + 5 * SH_W_GRP, tdb2, lv,
                                      tokens, accum, 0, 1);
    // K5: MFMA attention (reads lv + Apk bu-image; Apk rewritten only at K7)
    attn_k<<<384, 256, 0, stream>>>(lv, Apk, attnb);
    // K6: consensus RMW into accum
    cons_k<<<768, 256, 0, stream>>>(attnb, lv, accum);
    // K7: combine + dout + next-iter A-pack
    combine3<<<3072, 256, 0, stream>>>(accum, pos, lv, Apk, Apk + SH_A_TDOFF,
                                       dout, it == 11 ? 1 : 0);
  }
}

// Round 7
// 4731.129 us; speedup vs baseline: 1.1558x; 1.0723x over previous
//
#include <hip/hip_runtime.h>
#include <math.h>

// Problem constants: B=8, S=224, P=14, D=512, L=6, NPS=16, N=256, G=5, H=2048, iters=12
#define L6 6

typedef __attribute__((ext_vector_type(8))) short bf16x8;   // 8 bf16 in 4 VGPRs
typedef __attribute__((ext_vector_type(4))) float f32x4;    // MFMA accum

#define SH_W_GRP   2097152ull   // 512*2048 hi/lo bf16 (both W1 and W2)
#define SH_A_GRP   2097152ull   // 2048 tok * 512 d hi/lo
#define SH_A_TDOFF 10485760ull  // Atd offset inside Apk (5 groups)

// Exact gelu (erff): r10-proven epilogue.
__device__ __forceinline__ float gelu_exact(float x) {
  return 0.5f * x * (1.0f + erff(x * 0.70710678118654752f));
}

__device__ __forceinline__ unsigned short bf16_rn(float x) {
  unsigned u = __float_as_uint(x);
  unsigned r = u + 0x7FFFu + ((u >> 16) & 1u);
  return (unsigned short)(r >> 16);
}
__device__ __forceinline__ float bf16_f(unsigned short h) {
  return __uint_as_float(((unsigned)h) << 16);
}
__device__ __forceinline__ void split2(float x, unsigned short* h, unsigned short* l) {
  unsigned short hh = bf16_rn(x);
  *h = hh;
  *l = bf16_rn(x - bf16_f(hh));
}
__device__ __forceinline__ int4 pack8(const unsigned short* v) {
  return make_int4((int)((unsigned)v[0] | ((unsigned)v[1] << 16)),
                   (int)((unsigned)v[2] | ((unsigned)v[3] << 16)),
                   (int)((unsigned)v[4] | ((unsigned)v[5] << 16)),
                   (int)((unsigned)v[6] | ((unsigned)v[7] << 16)));
}

__device__ __forceinline__ void gload16(const void* g, void* l) {
  __builtin_amdgcn_global_load_lds(
      (const __attribute__((address_space(1))) void*)g,
      (__attribute__((address_space(3))) void*)l, 16, 0, 0);
}

// ---------------------------------------------------------------------------
// Patch embedding
// ---------------------------------------------------------------------------
__global__ __launch_bounds__(256) void patch_embed(
    const float* __restrict__ img, const float* __restrict__ Wp,
    const float* __restrict__ bp, float* __restrict__ tokens)
{
  __shared__ float xs[588];
  const int bn = blockIdx.x;
  const int b = bn >> 8, n = bn & 255;
  const int i = n >> 4, j = n & 15;
  for (int k = threadIdx.x; k < 588; k += 256) {
    int c = k % 3;
    int t = k / 3;
    int pc = t % 14;
    int pr = t / 14;
    xs[k] = img[(((size_t)(b * 3 + c) * 224) + (i * 14 + pr)) * 224 + (j * 14 + pc)];
  }
  __syncthreads();
  const int d0 = threadIdx.x, d1 = threadIdx.x + 256;
  float a0 = 0.f, a1 = 0.f;
  for (int k = 0; k < 588; ++k) {
    float x = xs[k];
    a0 = fmaf(x, Wp[(size_t)k * 512 + d0], a0);
    a1 = fmaf(x, Wp[(size_t)k * 512 + d1], a1);
  }
  tokens[(size_t)bn * 512 + d0] = a0 + bp[d0];
  tokens[(size_t)bn * 512 + d1] = a1 + bp[d1];
}

// ---------------------------------------------------------------------------
__global__ __launch_bounds__(256) void init_lv_kernel(
    const float* __restrict__ initl, float* __restrict__ lv)
{
  int f = blockIdx.x * 256 + threadIdx.x;
  int d4 = f & 127;
  int l = (f >> 15) % 6;
  float4 v = *(const float4*)(initl + (size_t)l * 512 + d4 * 4);
  *(float4*)(lv + (size_t)f * 4) = v;
}

// ---------------------------------------------------------------------------
// Startup norms: invn[bl][n] = 1/max(||lv[bl,n,:]||, 1e-12). One-shot;
// steady-state values produced by combine3's fused wave-reduce.
// ---------------------------------------------------------------------------
__global__ __launch_bounds__(256) void norm0_k(
    const float* __restrict__ lv, float* __restrict__ invn)
{
  int bl = blockIdx.x;
  int n = threadIdx.x;
  const float* row = lv + ((size_t)bl * 256 + n) * 512;
  float ss = 0.f;
  for (int k = 0; k < 512; k += 4) {
    float4 v = *(const float4*)(row + k);
    ss = fmaf(v.x, v.x, ss);
    ss = fmaf(v.y, v.y, ss);
    ss = fmaf(v.z, v.z, ss);
    ss = fmaf(v.w, v.w, ss);
  }
  invn[(size_t)bl * 256 + n] = 1.0f / fmaxf(sqrtf(ss), 1e-12f);
}

// ---------------------------------------------------------------------------
// Pack weights fp32 [G][K][N] -> hi/lo bf16 fragment-image.
// ---------------------------------------------------------------------------
__global__ __launch_bounds__(256) void pack_w(
    const float* __restrict__ src, short* __restrict__ dst, int KT, int NT)
{
  int sidx = blockIdx.x * 256 + threadIdx.x;
  int slot = sidx & 511;
  int blk = sidx >> 9;
  int kt = blk % KT;
  int rest = blk / KT;
  int nt = rest % NT;
  int g = rest / NT;
  int f = slot >> 6, lane = slot & 63;
  int N = NT * 128, K = KT * 32;
  int n = nt * 128 + f * 16 + (lane & 15);
  int k0 = kt * 32 + (lane >> 4) * 8;
  const float* s = src + ((size_t)g * K + k0) * N + n;
  unsigned short hi[8], lo[8];
#pragma unroll
  for (int j = 0; j < 8; ++j) split2(s[(size_t)j * N], &hi[j], &lo[j]);
  short* d = dst + (size_t)blk * 8192 + slot * 8;
  *(int4*)d = pack8(hi);
  *(int4*)(d + 4096) = pack8(lo);
}

// ---------------------------------------------------------------------------
// Startup A-pack (steady-state fused into combine3).
// ---------------------------------------------------------------------------
__global__ __launch_bounds__(256) void pack_A(
    const float* __restrict__ lv, const float* __restrict__ pos,
    short* __restrict__ Abu, short* __restrict__ Atd)
{
  const int bx = blockIdx.x;              // 0..1279
  const int lg = bx >> 8, mt = (bx >> 4) & 15, kt = bx & 15;
  const size_t blk = (size_t)bx * 8192;
#pragma unroll
  for (int ss = 0; ss < 2; ++ss) {
    int s = threadIdx.x + ss * 256;
    int f = s >> 6, l = s & 63;
    int m = mt * 128 + (f << 4) + (l & 15);
    int b = m >> 8, n = m & 255;
    int d = kt * 32 + ((l >> 4) << 3);
    const float* pbu = lv + ((size_t)(b * L6 + lg) * 256 + n) * 512 + d;
    const float* ptd = lv + ((size_t)(b * L6 + lg + 1) * 256 + n) * 512 + d;
    const float* pp = pos + (size_t)n * 512 + d;
    float4 u0 = *(const float4*)pbu;
    float4 u1 = *(const float4*)(pbu + 4);
    float xv[8] = {u0.x, u0.y, u0.z, u0.w, u1.x, u1.y, u1.z, u1.w};
    unsigned short hi[8], lo[8];
#pragma unroll
    for (int j = 0; j < 8; ++j) split2(xv[j], &hi[j], &lo[j]);
    *(int4*)(Abu + blk + s * 8) = pack8(hi);
    *(int4*)(Abu + blk + 4096 + s * 8) = pack8(lo);
    float4 v0 = *(const float4*)ptd;
    float4 v1 = *(const float4*)(ptd + 4);
    float4 p0 = *(const float4*)pp;
    float4 p1 = *(const float4*)(pp + 4);
    float yv[8] = {v0.x + p0.x, v0.y + p0.y, v0.z + p0.z, v0.w + p0.w,
                   v1.x + p1.x, v1.y + p1.y, v1.z + p1.z, v1.w + p1.w};
#pragma unroll
    for (int j = 0; j < 8; ++j) split2(yv[j], &hi[j], &lo[j]);
    *(int4*)(Atd + blk + s * 8) = pack8(hi);
    *(int4*)(Atd + blk + 4096 + s * 8) = pack8(lo);
  }
}

// ---------------------------------------------------------------------------
// FF1: h^T = W1^T @ lv^T, bf16x2, 128x128 block, single-buf LDS 32KB.
// r2-proven config (109us, MfmaUtil 24%, occ 33%). r1/r3 pipelining variants
// both regressed — do not re-add.
// ---------------------------------------------------------------------------
__global__ __launch_bounds__(256, 3) void ff1_k(
    const short* __restrict__ Wa, const short* __restrict__ Ap,
    const float* __restrict__ b1, short* __restrict__ hpk)
{
  __shared__ __align__(16) short SA[8192];
  __shared__ __align__(16) short SB[8192];
  const int per_x = gridDim.x >> 3;
  const int gid = (blockIdx.x & 7) * per_x + (blockIdx.x >> 3);
  const int tt = gid & 15;
  const int tile = gid >> 4;
  const int ht = tile & 15;
  const int z = tile >> 4;
  const int tid = threadIdx.x, lane = tid & 63, w = tid >> 6;
  const int wm = (w >> 1) * 64, wn = (w & 1) * 64;
  const short* ga = Wa + (size_t)(z * 16 + ht) * 16 * 8192;
  const short* gb = Ap + (size_t)(z * 16 + tt) * 16 * 8192;
  const int soff = w * 4096 + lane * 16;

  f32x4 acc[4][4];
#pragma unroll
  for (int i = 0; i < 4; ++i)
#pragma unroll
    for (int j = 0; j < 4; ++j) acc[i][j] = (f32x4)(0.0f);

  for (int kt = 0; kt < 16; ++kt) {
    __syncthreads();
    const char* pa = (const char*)(ga + (size_t)kt * 8192);
    const char* pb = (const char*)(gb + (size_t)kt * 8192);
#pragma unroll
    for (int c = 0; c < 4; ++c) {
      gload16(pa + soff + c * 1024, (char*)SA + w * 4096 + c * 1024);
      gload16(pb + soff + c * 1024, (char*)SB + w * 4096 + c * 1024);
    }
    __syncthreads();
    bf16x8 ah[4], al[4];
#pragma unroll
    for (int i = 0; i < 4; ++i) {
      int f = (wm >> 4) + i;
      ah[i] = *(const bf16x8*)&SA[f * 512 + lane * 8];
      al[i] = *(const bf16x8*)&SA[4096 + f * 512 + lane * 8];
    }
#pragma unroll
    for (int jp = 0; jp < 2; ++jp) {
      bf16x8 bh[2], bl[2];
#pragma unroll
      for (int j2 = 0; j2 < 2; ++j2) {
        int f = (wn >> 4) + jp * 2 + j2;
        bh[j2] = *(const bf16x8*)&SB[f * 512 + lane * 8];
        bl[j2] = *(const bf16x8*)&SB[4096 + f * 512 + lane * 8];
      }
      // pass 1: A_hi * B_hi (8 independent MFMAs)
#pragma unroll
      for (int j2 = 0; j2 < 2; ++j2)
#pragma unroll
        for (int i = 0; i < 4; ++i)
          acc[i][jp * 2 + j2] = __builtin_amdgcn_mfma_f32_16x16x32_bf16(
              ah[i], bh[j2], acc[i][jp * 2 + j2], 0, 0, 0);
      // pass 2: A_lo * B_hi
#pragma unroll
      for (int j2 = 0; j2 < 2; ++j2)
#pragma unroll
        for (int i = 0; i < 4; ++i)
          acc[i][jp * 2 + j2] = __builtin_amdgcn_mfma_f32_16x16x32_bf16(
              al[i], bh[j2], acc[i][jp * 2 + j2], 0, 0, 0);
      // pass 3: A_hi * B_lo
#pragma unroll
      for (int j2 = 0; j2 < 2; ++j2)
#pragma unroll
        for (int i = 0; i < 4; ++i)
          acc[i][jp * 2 + j2] = __builtin_amdgcn_mfma_f32_16x16x32_bf16(
              ah[i], bl[j2], acc[i][jp * 2 + j2], 0, 0, 0);
    }
  }

  const int q = lane >> 4, t = lane & 15;
  const float* b1g = b1 + (size_t)z * 2048;
#pragma unroll
  for (int i = 0; i < 4; ++i) {
    int Hb = ht * 128 + wm + i * 16 + q * 4;
    float4 bv = *(const float4*)(b1g + Hb);
    float bb[4] = {bv.x, bv.y, bv.z, bv.w};
    int kt2 = Hb >> 5;
    int g2 = (Hb >> 3) & 3;
    int jb = Hb & 7;                       // 0 or 4
    size_t blkbase = ((size_t)(z * 16 + tt) * 64 + kt2) * 8192;
#pragma unroll
    for (int j = 0; j < 4; ++j) {
      int f2 = (wn >> 4) + j;
      size_t off = blkbase + (size_t)(f2 * 64 + g2 * 16 + t) * 8 + jb;
      unsigned short hi[4], lo[4];
#pragma unroll
      for (int r = 0; r < 4; ++r) {
        float x = gelu_exact(acc[i][j][r] + bb[r]);
        split2(x, &hi[r], &lo[r]);
      }
      *(uint2*)(hpk + off) =
          make_uint2((unsigned)hi[0] | ((unsigned)hi[1] << 16),
                     (unsigned)hi[2] | ((unsigned)hi[3] << 16));
      *(uint2*)(hpk + off + 4096) =
          make_uint2((unsigned)lo[0] | ((unsigned)lo[1] << 16),
                     (unsigned)lo[2] | ((unsigned)lo[3] << 16));
    }
  }
}

// ---------------------------------------------------------------------------
// Attention r7: MFMA Gram with norm table. Norms hoisted out of the k-loop
// (invn, produced by combine3 / norm0_k) — the l<5 path issues ZERO fp32
// reads; B-panel gload16'd straight from Apk's bu-image (levels 0..4 =
// packed current lv, intact until K7). A-frags are a row-subset of the same
// panel. Level 5 packs on the fly via split2. r6's fused fp32 norm reads
// doubled the VMEM stream and kept attn at ~95us — this removes them.
// ---------------------------------------------------------------------------
__global__ __launch_bounds__(256, 3) void attn_k(
    const float* __restrict__ lv, const short* __restrict__ Apk,
    const float* __restrict__ invn, float* __restrict__ attnb)
{
  __shared__ __align__(16) short Bhi[8192];   // 16 frags x 64 lanes x 8
  __shared__ __align__(16) short Blo[8192];
  __shared__ float scL[256];
  __shared__ float red[32][4];
  const int a = blockIdx.x;
  const int s = a >> 3;
  const int b = a & 7;                 // batch == XCD group
  const int l = s >> 3;                // level 0..5
  const int bl = b * 6 + l;
  const int i0 = (s & 7) * 32;
  const float* base = lv + (size_t)bl * 131072;
  const int tid = threadIdx.x, lane = tid & 63, w = tid >> 6;
  const int q = lane >> 4, c = lane & 15;

  scL[tid] = invn[(size_t)bl * 256 + tid];   // one row scale per thread

  f32x4 acc[2][4];
#pragma unroll
  for (int i = 0; i < 2; ++i)
#pragma unroll
    for (int j = 0; j < 4; ++j) acc[i][j] = (f32x4)(0.0f);

  // Apk bu-image sub-blocks for this (b,l): tokens n 0..127 -> tile 2b,
  // n 128..255 -> tile 2b+1. Valid only for l<5.
  const short* src0 = Apk + ((size_t)(l * 16 + 2 * b) * 16) * 8192;
  const short* src1 = Apk + ((size_t)(l * 16 + 2 * b + 1) * 16) * 8192;

  for (int kt = 0; kt < 16; ++kt) {
    __syncthreads();                    // prev step's LDS reads done
    if (l < 5) {
      const char* p0 = (const char*)(src0 + (size_t)kt * 8192);
      const char* p1 = (const char*)(src1 + (size_t)kt * 8192);
      gload16(p0 + tid * 16,         (char*)Bhi + tid * 16);
      gload16(p0 + 4096 + tid * 16,  (char*)Bhi + 4096 + tid * 16);
      gload16(p0 + 8192 + tid * 16,  (char*)Blo + tid * 16);
      gload16(p0 + 12288 + tid * 16, (char*)Blo + 4096 + tid * 16);
      gload16(p1 + tid * 16,         (char*)Bhi + 8192 + tid * 16);
      gload16(p1 + 4096 + tid * 16,  (char*)Bhi + 12288 + tid * 16);
      gload16(p1 + 8192 + tid * 16,  (char*)Blo + 8192 + tid * 16);
      gload16(p1 + 12288 + tid * 16, (char*)Blo + 12288 + tid * 16);
    } else {
      const int k0 = kt * 32;
#pragma unroll
      for (int it = 0; it < 8; ++it) {
        int f = it * 256 + tid;
        int j = f >> 3, c4 = f & 7;
        float4 v = *(const float4*)(base + (size_t)j * 512 + k0 + c4 * 4);
        unsigned short hi[4], lo[4];
        split2(v.x, &hi[0], &lo[0]);
        split2(v.y, &hi[1], &lo[1]);
        split2(v.z, &hi[2], &lo[2]);
        split2(v.w, &hi[3], &lo[3]);
        int fg = j >> 4;
        int la = (c4 >> 1) * 16 + (j & 15);
        int half = (c4 & 1) * 4;
        *(uint2*)&Bhi[fg * 512 + la * 8 + half] =
            make_uint2((unsigned)hi[0] | ((unsigned)hi[1] << 16),
                       (unsigned)hi[2] | ((unsigned)hi[3] << 16));
        *(uint2*)&Blo[fg * 512 + la * 8 + half] =
            make_uint2((unsigned)lo[0] | ((unsigned)lo[1] << 16),
                       (unsigned)lo[2] | ((unsigned)lo[3] << 16));
      }
    }
    __syncthreads();                    // staging complete
    bf16x8 ah[2], al[2], bh[4], blv[4];
#pragma unroll
    for (int i = 0; i < 2; ++i) {
      int fg = (i0 >> 4) + i;
      ah[i] = *(const bf16x8*)&Bhi[fg * 512 + lane * 8];
      al[i] = *(const bf16x8*)&Blo[fg * 512 + lane * 8];
    }
#pragma unroll
    for (int j = 0; j < 4; ++j) {
      int fg = w * 4 + j;
      bh[j] = *(const bf16x8*)&Bhi[fg * 512 + lane * 8];
      blv[j] = *(const bf16x8*)&Blo[fg * 512 + lane * 8];
    }
#pragma unroll
    for (int j = 0; j < 4; ++j)
#pragma unroll
      for (int i = 0; i < 2; ++i)
        acc[i][j] = __builtin_amdgcn_mfma_f32_16x16x32_bf16(
            ah[i], bh[j], acc[i][j], 0, 0, 0);
#pragma unroll
    for (int j = 0; j < 4; ++j)
#pragma unroll
      for (int i = 0; i < 2; ++i)
        acc[i][j] = __builtin_amdgcn_mfma_f32_16x16x32_bf16(
            al[i], bh[j], acc[i][j], 0, 0, 0);
#pragma unroll
    for (int j = 0; j < 4; ++j)
#pragma unroll
      for (int i = 0; i < 2; ++i)
        acc[i][j] = __builtin_amdgcn_mfma_f32_16x16x32_bf16(
            ah[i], blv[j], acc[i][j], 0, 0, 0);
  }
  __syncthreads();                      // scL writes visible (also from loop)

  const float rs = 0.04419417382415922f;  // 512^-0.5
  // scale + diag; value at (ai,bj,r): i = i0+ai*16+q*4+r, j = w*64+bj*16+c
#pragma unroll
  for (int ai = 0; ai < 2; ++ai)
#pragma unroll
    for (int bj = 0; bj < 4; ++bj)
#pragma unroll
      for (int r = 0; r < 4; ++r) {
        int i = i0 + ai * 16 + q * 4 + r;
        int j = w * 64 + bj * 16 + c;
        float sv = acc[ai][bj][r] * scL[j] * rs;
        if (j == i) sv = -0.0005f;
        acc[ai][bj][r] = sv;
      }
  // wave-local row max (over this wave's 64 j), then cross-wave via red
  float mx[2][4];
#pragma unroll
  for (int ai = 0; ai < 2; ++ai)
#pragma unroll
    for (int r = 0; r < 4; ++r) {
      float m = fmaxf(fmaxf(acc[ai][0][r], acc[ai][1][r]),
                      fmaxf(acc[ai][2][r], acc[ai][3][r]));
      m = fmaxf(m, __shfl_xor(m, 1));
      m = fmaxf(m, __shfl_xor(m, 2));
      m = fmaxf(m, __shfl_xor(m, 4));
      m = fmaxf(m, __shfl_xor(m, 8));
      mx[ai][r] = m;
    }
  if (c == 0) {
#pragma unroll
    for (int ai = 0; ai < 2; ++ai)
#pragma unroll
      for (int r = 0; r < 4; ++r) red[ai * 16 + q * 4 + r][w] = mx[ai][r];
  }
  __syncthreads();
#pragma unroll
  for (int ai = 0; ai < 2; ++ai)
#pragma unroll
    for (int r = 0; r < 4; ++r) {
      int row = ai * 16 + q * 4 + r;
      mx[ai][r] = fmaxf(fmaxf(red[row][0], red[row][1]),
                        fmaxf(red[row][2], red[row][3]));
    }
  __syncthreads();                      // before red reuse for sums
  float sm[2][4];
#pragma unroll
  for (int ai = 0; ai < 2; ++ai)
#pragma unroll
    for (int r = 0; r < 4; ++r) {
      float t = 0.f;
#pragma unroll
      for (int bj = 0; bj < 4; ++bj) {
        float e = expf(acc[ai][bj][r] - mx[ai][r]);
        acc[ai][bj][r] = e;
        t += e;
      }
      t += __shfl_xor(t, 1);
      t += __shfl_xor(t, 2);
      t += __shfl_xor(t, 4);
      t += __shfl_xor(t, 8);
      sm[ai][r] = t;
    }
  if (c == 0) {
#pragma unroll
    for (int ai = 0; ai < 2; ++ai)
#pragma unroll
      for (int r = 0; r < 4; ++r) red[ai * 16 + q * 4 + r][w] = sm[ai][r];
  }
  __syncthreads();
  float* ob = attnb + (size_t)bl * 65536;
#pragma unroll
  for (int ai = 0; ai < 2; ++ai)
#pragma unroll
    for (int r = 0; r < 4; ++r) {
      int row = ai * 16 + q * 4 + r;
      float S = red[row][0] + red[row][1] + red[row][2] + red[row][3];
      float inv = 1.0f / S;
      int i = i0 + row;
#pragma unroll
      for (int bj = 0; bj < 4; ++bj) {
        int j = w * 64 + bj * 16 + c;
        ob[(size_t)i * 256 + j] = acc[ai][bj][r] * inv;
      }
    }
}

// ---------------------------------------------------------------------------
// Consensus: accum += attnb @ lv (pure RMW). Grid 768, XCD-grouped by bl.
// ---------------------------------------------------------------------------
__global__ __launch_bounds__(256) void cons_k(
    const float* __restrict__ attnb, const float* __restrict__ lv,
    float* __restrict__ accum)
{
  __shared__ __align__(16) char smemraw[25088];
  const int a = blockIdx.x;
  const int s = a >> 3;
  const int bl = (a & 7) * 6 + (s >> 4);
  const int tile = s & 15;
  int it0 = (tile >> 2) * 64;
  int dt0 = (tile & 3) * 128;
  const float* A = attnb + (size_t)bl * 65536;
  const float* Bm = lv + (size_t)bl * 131072;
  float (*Ast)[68] = (float(*)[68])smemraw;
  float (*Bs)[128] = (float(*)[128])(smemraw + 8704);
  const int tid = threadIdx.x;
  const int ty = tid >> 4, tx = tid & 15;
  float acc[4][8];
#pragma unroll
  for (int i = 0; i < 4; ++i)
#pragma unroll
    for (int j = 0; j < 8; ++j) acc[i][j] = 0.f;

  for (int k0 = 0; k0 < 256; k0 += 32) {
#pragma unroll
    for (int it = 0; it < 2; ++it) {
      int f = it * 256 + tid;
      int r = f >> 3, c4 = f & 7;
      float4 v = *(const float4*)(A + (size_t)(it0 + r) * 256 + k0 + c4 * 4);
      Ast[c4 * 4 + 0][r] = v.x;
      Ast[c4 * 4 + 1][r] = v.y;
      Ast[c4 * 4 + 2][r] = v.z;
      Ast[c4 * 4 + 3][r] = v.w;
    }
#pragma unroll
    for (int it = 0; it < 4; ++it) {
      int kr = (tid >> 5) + it * 8;
      int c4 = tid & 31;
      *(float4*)&Bs[kr][c4 * 4] =
          *(const float4*)(Bm + (size_t)(k0 + kr) * 512 + dt0 + c4 * 4);
    }
    __syncthreads();
#pragma unroll 8
    for (int k = 0; k < 32; ++k) {
      float4 av = *(const float4*)&Ast[k][ty * 4];
      float4 b0 = *(const float4*)&Bs[k][tx * 4];
      float4 b1 = *(const float4*)&Bs[k][64 + tx * 4];
      float avv[4] = {av.x, av.y, av.z, av.w};
      float bv[8] = {b0.x, b0.y, b0.z, b0.w, b1.x, b1.y, b1.z, b1.w};
#pragma unroll
      for (int i = 0; i < 4; ++i)
#pragma unroll
        for (int j = 0; j < 8; ++j)
          acc[i][j] = fmaf(avv[i], bv[j], acc[i][j]);
    }
    __syncthreads();
  }
#pragma unroll
  for (int ii = 0; ii < 4; ++ii) {
    int i = it0 + ty * 4 + ii;
    float* arow = accum + (size_t)bl * 131072 + (size_t)i * 512 + dt0;
#pragma unroll
    for (int j = 0; j < 4; ++j) arow[tx * 4 + j] += acc[ii][j];
#pragma unroll
    for (int j = 0; j < 4; ++j) arow[64 + tx * 4 + j] += acc[ii][4 + j];
  }
}

// ---------------------------------------------------------------------------
// FF2: 64(token) x 128(outd) block, 640 blocks, single-buf LDS 24KB.
// r2-proven: launch_bounds(256,4) + product-pass reorder with j-pairs.
//  emode 0 (bu):      accum = lv + v            (store, levels 1..5)
//  emode 1 (td):      l==0: accum=lv+tokens+v;  else accum += v
// ---------------------------------------------------------------------------
__global__ __launch_bounds__(256, 4) void mfma_ff2(
    const short* __restrict__ hpk, const short* __restrict__ Wb,
    const float* __restrict__ b2, const float* __restrict__ lv,
    const float* __restrict__ tokens, float* __restrict__ accum,
    int olvbase, int emode)
{
  const int per_x = gridDim.x >> 3;
  const int gid = (blockIdx.x & 7) * per_x + (blockIdx.x >> 3);
  const int nt2 = gid & 3;
  const int tile = gid >> 2;
  const int mt2 = tile & 31;          // 64-token tiles
  const int z = tile >> 5;

  __shared__ __align__(16) short SA[4096];   // hi 2048 | lo 2048
  __shared__ __align__(16) short SB[8192];   // hi 4096 | lo 4096
  const int tid = threadIdx.x, lane = tid & 63, w = tid >> 6;
  const int wm = (w >> 1) * 32, wn = (w & 1) * 64;
  const short* gaBase = hpk + (size_t)(z * 16 + (mt2 >> 1)) * 64 * 8192
                        + (size_t)(mt2 & 1) * 2048;
  const short* gb = Wb + (size_t)(z * 4 + nt2) * 64 * 8192;

  f32x4 acc[2][4];
#pragma unroll
  for (int i = 0; i < 2; ++i)
#pragma unroll
    for (int j = 0; j < 4; ++j) acc[i][j] = (f32x4)(0.0f);

  for (int kt = 0; kt < 64; ++kt) {
    __syncthreads();
    const char* pa = (const char*)(gaBase + (size_t)kt * 8192);
    const char* pb = (const char*)(gb + (size_t)kt * 8192);
    gload16(pa + w * 1024 + lane * 16, (char*)SA + w * 1024);
    gload16(pa + 8192 + w * 1024 + lane * 16, (char*)SA + 4096 + w * 1024);
#pragma unroll
    for (int c = 0; c < 4; ++c)
      gload16(pb + w * 4096 + c * 1024 + lane * 16,
              (char*)SB + w * 4096 + c * 1024);
    __syncthreads();
    bf16x8 ah[2], al[2];
#pragma unroll
    for (int i = 0; i < 2; ++i) {
      int f = (wm >> 4) + i;
      ah[i] = *(const bf16x8*)&SA[f * 512 + lane * 8];
      al[i] = *(const bf16x8*)&SA[2048 + f * 512 + lane * 8];
    }
#pragma unroll
    for (int jp = 0; jp < 2; ++jp) {
      bf16x8 bh[2], bl[2];
#pragma unroll
      for (int j2 = 0; j2 < 2; ++j2) {
        int f = (wn >> 4) + jp * 2 + j2;
        bh[j2] = *(const bf16x8*)&SB[f * 512 + lane * 8];
        bl[j2] = *(const bf16x8*)&SB[4096 + f * 512 + lane * 8];
      }
#pragma unroll
      for (int j2 = 0; j2 < 2; ++j2)
#pragma unroll
        for (int i = 0; i < 2; ++i)
          acc[i][jp * 2 + j2] = __builtin_amdgcn_mfma_f32_16x16x32_bf16(
              ah[i], bh[j2], acc[i][jp * 2 + j2], 0, 0, 0);
#pragma unroll
      for (int j2 = 0; j2 < 2; ++j2)
#pragma unroll
        for (int i = 0; i < 2; ++i)
          acc[i][jp * 2 + j2] = __builtin_amdgcn_mfma_f32_16x16x32_bf16(
              al[i], bh[j2], acc[i][jp * 2 + j2], 0, 0, 0);
#pragma unroll
      for (int j2 = 0; j2 < 2; ++j2)
#pragma unroll
        for (int i = 0; i < 2; ++i)
          acc[i][jp * 2 + j2] = __builtin_amdgcn_mfma_f32_16x16x32_bf16(
              ah[i], bl[j2], acc[i][jp * 2 + j2], 0, 0, 0);
    }
  }

  const int q = lane >> 4, t = lane & 15;
  const float* b2g = b2 + (size_t)z * 512;
  const int level = olvbase + z;
#pragma unroll
  for (int i = 0; i < 2; ++i) {
#pragma unroll
    for (int r = 0; r < 4; ++r) {
      int m = mt2 * 64 + wm + i * 16 + q * 4 + r;
      int b = m >> 8, n = m & 255;
      size_t rowoff = ((size_t)(b * L6 + level) * 256 + n) * 512;
      float* arow = accum + rowoff;
      const float* lrow = lv + rowoff;
      const float* trow = tokens + (size_t)m * 512;
#pragma unroll
      for (int j = 0; j < 4; ++j) {
        int col = nt2 * 128 + wn + j * 16 + t;
        float v = acc[i][j][r] + b2g[col];
        if (emode == 0)                       arow[col] = lrow[col] + v;
        else if (level == 0)                  arow[col] = lrow[col] + trow[col] + v;
        else                                  arow[col] += v;
      }
    }
  }
}

// ---------------------------------------------------------------------------
// combine3: lv = accum/contrib, write dout on last iter, fused next-iter
// A-packing, and (r7) fused exact-fp32 row-norm via 64-lane butterfly
// (d8 == lane within wave; one wave holds exactly one (b,l,n) row).
// ---------------------------------------------------------------------------
__global__ __launch_bounds__(256) void combine3(
    const float* __restrict__ accum, const float* __restrict__ pos,
    float* __restrict__ lv_out, short* __restrict__ Abu,
    short* __restrict__ Atd, float* __restrict__ invn,
    float* __restrict__ dout, int last)
{
  int t = blockIdx.x * 256 + threadIdx.x;   // 786,432 total
  int d8 = t & 63;
  int n = (t >> 6) & 255;
  int v = t >> 14;                          // b*6 + l, 0..47
  int l = v % 6, b = v / 6;
  int bn = (b << 8) | n;
  size_t idx = ((size_t)v * 256 + n) * 512 + d8 * 8;
  float4 a0 = *(const float4*)(accum + idx);
  float4 a1 = *(const float4*)(accum + idx + 4);
  float sc = (l == 5) ? (1.0f / 3.0f) : 0.25f;
  float r[8];
  r[0] = a0.x * sc; r[1] = a0.y * sc; r[2] = a0.z * sc; r[3] = a0.w * sc;
  r[4] = a1.x * sc; r[5] = a1.y * sc; r[6] = a1.z * sc; r[7] = a1.w * sc;
  *(float4*)(lv_out + idx) = make_float4(r[0], r[1], r[2], r[3]);
  *(float4*)(lv_out + idx + 4) = make_float4(r[4], r[5], r[6], r[7]);
  if (last) {
    float* dp = dout + ((size_t)bn * 6 + l) * 512 + d8 * 8;
    *(float4*)dp = make_float4(r[0], r[1], r[2], r[3]);
    *(float4*)(dp + 4) = make_float4(r[4], r[5], r[6], r[7]);
  }
  // fused row norm: wave == one (v,n) row (d8 = lane)
  {
    float s8 = 0.f;
#pragma unroll
    for (int j = 0; j < 8; ++j) s8 = fmaf(r[j], r[j], s8);
#pragma unroll
    for (int o = 1; o < 64; o <<= 1) s8 += __shfl_xor(s8, o);
    if (d8 == 0) invn[(size_t)v * 256 + n] = 1.0f / fmaxf(sqrtf(s8), 1e-12f);
  }
  int m = bn;
  int mt = m >> 7;
  int kt = d8 >> 2;
  int s = (((m & 127) >> 4) << 6) | (((d8 & 3) << 4) | (m & 15));
  unsigned short hi[8], lo[8];
  if (l < 5) {
    size_t blk = ((size_t)(l * 16 + mt) * 16 + kt) * 8192;
#pragma unroll
    for (int j = 0; j < 8; ++j) split2(r[j], &hi[j], &lo[j]);
    *(int4*)(Abu + blk + s * 8) = pack8(hi);
    *(int4*)(Abu + blk + 4096 + s * 8) = pack8(lo);
  }
  if (l >= 1) {
    const float* pp = pos + (size_t)n * 512 + d8 * 8;
    float4 p0 = *(const float4*)pp;
    float4 p1 = *(const float4*)(pp + 4);
    float y[8] = {r[0] + p0.x, r[1] + p0.y, r[2] + p0.z, r[3] + p0.w,
                  r[4] + p1.x, r[5] + p1.y, r[6] + p1.z, r[7] + p1.w};
    size_t blk = ((size_t)((l - 1) * 16 + mt) * 16 + kt) * 8192;
#pragma unroll
    for (int j = 0; j < 8; ++j) split2(y[j], &hi[j], &lo[j]);
    *(int4*)(Atd + blk + s * 8) = pack8(hi);
    *(int4*)(Atd + blk + 4096 + s * 8) = pack8(lo);
  }
}

// ---------------------------------------------------------------------------
extern "C" void kernel_launch(void* const* d_in, const int* in_sizes, int n_in,
                              void* d_out, int out_size, void* d_ws, size_t ws_size,
                              hipStream_t stream)
{
  const float* img   = (const float*)d_in[0];
  const float* Wp    = (const float*)d_in[1];
  const float* bp    = (const float*)d_in[2];
  const float* pos   = (const float*)d_in[3];
  const float* initl = (const float*)d_in[4];
  const float* buW1  = (const float*)d_in[5];
  const float* bub1  = (const float*)d_in[6];
  const float* buW2  = (const float*)d_in[7];
  const float* bub2  = (const float*)d_in[8];
  const float* tdW1  = (const float*)d_in[9];
  const float* tdb1  = (const float*)d_in[10];
  const float* tdW2  = (const float*)d_in[11];
  const float* tdb2  = (const float*)d_in[12];

  float* ws = (float*)d_ws;
  const size_t LV = (size_t)8 * 6 * 256 * 512;   // 6,291,456 floats
  float* lv     = ws;
  float* tokens = lv + LV;                        // 1,048,576
  float* accum  = tokens + 1048576ull;            // 6,291,456
  short* W1all  = (short*)(accum + LV);           // 20,971,520 shorts
  short* W2all  = W1all + 20971520ull;            // 20,971,520 shorts
  short* Apk    = W2all + 20971520ull;            // 20,971,520 shorts
  short* hall   = Apk + 20971520ull;              // 41,943,040 shorts (5z hi/lo)
  float* invn   = (float*)(hall + 41943040ull);   // 48*256 f32 = 49,152 B
  // total = 264,241,152 + 49,152 = 264,290,304 B == proven capacity

  // attnb aliases hall's upper half (12.6 MB needed, 42 MB available);
  // it lives only between attn_k and cons_k, and hall is rewritten by the
  // NEXT iteration's ff1 passes after cons_k has consumed it.
  float* attnb = (float*)(hall + 20971520ull);
  float* dout  = (float*)d_out;

  pack_w<<<2560, 256, 0, stream>>>(buW1, W1all, 16, 16);
  pack_w<<<2560, 256, 0, stream>>>(tdW1, W1all + 5 * SH_W_GRP, 16, 16);
  pack_w<<<2560, 256, 0, stream>>>(buW2, W2all, 64, 4);
  pack_w<<<2560, 256, 0, stream>>>(tdW2, W2all + 5 * SH_W_GRP, 64, 4);

  patch_embed<<<2048, 256, 0, stream>>>(img, Wp, bp, tokens);
  init_lv_kernel<<<6144, 256, 0, stream>>>(initl, lv);
  norm0_k<<<48, 256, 0, stream>>>(lv, invn);
  pack_A<<<1280, 256, 0, stream>>>(lv, pos, Apk, Apk + SH_A_TDOFF);

  for (int it = 0; it < 12; ++it) {
    // K1: ff1-bu (fills hall)
    ff1_k<<<1280, 256, 0, stream>>>(W1all, Apk, bub1, hall);
    // K2: ff2-bu emode0 (store accum = lv + v, levels 1..5)
    mfma_ff2<<<640, 256, 0, stream>>>(hall, W2all, bub2, lv, tokens, accum, 1, 0);
    // K3: ff1-td (refills hall)
    ff1_k<<<1280, 256, 0, stream>>>(W1all + 5 * SH_W_GRP, Apk + SH_A_TDOFF,
                                    tdb1, hall);
    // K4: ff2-td emode1 (level0 store lv+tokens+v; levels 1..4 RMW)
    mfma_ff2<<<640, 256, 0, stream>>>(hall, W2all + 5 * SH_W_GRP, tdb2, lv,
                                      tokens, accum, 0, 1);
    // K5: MFMA attention (reads Apk bu-image + invn; lv only for level 5)
    attn_k<<<384, 256, 0, stream>>>(lv, Apk, invn, attnb);
    // K6: consensus RMW into accum
    cons_k<<<768, 256, 0, stream>>>(attnb, lv, accum);
    // K7: combine + dout + next-iter A-pack + fused norms
    combine3<<<3072, 256, 0, stream>>>(accum, pos, lv, Apk, Apk + SH_A_TDOFF,
                                       invn, dout, it == 11 ? 1 : 0);
  }
}